// Round 4
// baseline (5010.213 us; speedup 1.0000x reference)
//
#include <hip/hip_runtime.h>

#define NB_MAX 1024      // max total buckets (A + X)
#define ROWS_A 96        // rows per A-bucket  (LDS acc = 48 KB)
#define ROWS_X 64        // rows per X-bucket  (LDS acc = 32 KB)
#define TILE_EDGES 16384 // edges per partition block (1024 thr x 16)

// ---- bf16 helpers: table uint at [row][l] packs cols (l, l+64) -------------
__device__ __forceinline__ float blo(unsigned u) { return __uint_as_float(u << 16); }
__device__ __forceinline__ float bhi(unsigned u) { return __uint_as_float(u & 0xffff0000u); }
__device__ __forceinline__ unsigned pack_bf16(float x, float y) {
    unsigned ux = __float_as_uint(x); ux += 0x7fffu + ((ux >> 16) & 1u);
    unsigned uy = __float_as_uint(y); uy += 0x7fffu + ((uy >> 16) & 1u);
    return (ux >> 16) | (uy & 0xffff0000u);
}

// ---------------------------------------------------------------------------
// Bucket histogram (LDS-aggregated), A and X edges in one pass.
// ---------------------------------------------------------------------------
__global__ __launch_bounds__(256) void hist_kernel(
    const int* __restrict__ Arow, int nA, const int* __restrict__ Xrow, int nX,
    int nbA, int nb, int* __restrict__ gcnt) {
    __shared__ int cnt[NB_MAX];
    for (int t = threadIdx.x; t < nb; t += 256) cnt[t] = 0;
    __syncthreads();
    int tot = nA + nX;
    for (int i = blockIdx.x * 256 + threadIdx.x; i < tot; i += gridDim.x * 256) {
        int b = (i < nA) ? (Arow[i] / ROWS_A) : (nbA + Xrow[i - nA] / ROWS_X);
        atomicAdd(&cnt[b], 1);
    }
    __syncthreads();
    for (int t = threadIdx.x; t < nb; t += 256)
        if (cnt[t]) atomicAdd(&gcnt[t], cnt[t]);
}

// ---------------------------------------------------------------------------
// Single-block exclusive scan over nb bucket counts -> boff[0..nb], gcur.
// ---------------------------------------------------------------------------
__global__ __launch_bounds__(1024) void scan_kernel(
    const int* __restrict__ gcnt, int* __restrict__ boff, int* __restrict__ gcur, int nb) {
    __shared__ int wsum[16];
    __shared__ int carry_s;
    int tid = threadIdx.x, lane = tid & 63, w = tid >> 6;
    if (tid == 0) { carry_s = 0; boff[0] = 0; }
    __syncthreads();
    for (int base = 0; base < nb; base += 1024) {
        int i = base + tid;
        int x = (i < nb) ? gcnt[i] : 0;
        int v = x;
        #pragma unroll
        for (int d = 1; d < 64; d <<= 1) {
            int t = __shfl_up(v, d);
            if (lane >= d) v += t;
        }
        if (lane == 63) wsum[w] = v;
        __syncthreads();
        if (tid == 0) {
            int a = carry_s;
            #pragma unroll
            for (int j = 0; j < 16; ++j) { int t = wsum[j]; wsum[j] = a; a += t; }
            carry_s = a;
        }
        __syncthreads();
        int incl = v + wsum[w];
        if (i < nb) { boff[i + 1] = incl; gcur[i] = incl - x; }
        __syncthreads();
    }
}

// ---------------------------------------------------------------------------
// Partition edges into bucket-contiguous ebuf with per-block run reservation:
// phase A: LDS-count tile; phase B: one atomicAdd per touched bucket reserves
// a contiguous run; phase C: re-read edges, write into the run. Writes to a
// bucket land in ~160 B contiguous runs -> L2 write-combining, low WRITE_SIZE.
// Record: x = (row_local << 25) | col, y = bits(val).
// ---------------------------------------------------------------------------
__global__ __launch_bounds__(1024) void partition_kernel(
    const int* __restrict__ Arow, const int* __restrict__ Acol, const float* __restrict__ Aval, int nA,
    const int* __restrict__ Xrow, const int* __restrict__ Xcol, const float* __restrict__ Xval, int nX,
    int nbA, int nb, int* __restrict__ gcur, uint2* __restrict__ ebuf) {
    __shared__ int cnt[NB_MAX];
    __shared__ int rbase[NB_MAX];
    for (int t = threadIdx.x; t < nb; t += 1024) cnt[t] = 0;
    __syncthreads();
    int tot = nA + nX;
    int t0 = blockIdx.x * TILE_EDGES;
    #pragma unroll 4
    for (int k = 0; k < 16; ++k) {
        int i = t0 + k * 1024 + threadIdx.x;
        if (i < tot) {
            int b = (i < nA) ? (Arow[i] / ROWS_A) : (nbA + Xrow[i - nA] / ROWS_X);
            atomicAdd(&cnt[b], 1);
        }
    }
    __syncthreads();
    for (int t = threadIdx.x; t < nb; t += 1024) {
        int c = cnt[t];
        rbase[t] = c ? atomicAdd(&gcur[t], c) : 0;
        cnt[t] = 0;
    }
    __syncthreads();
    #pragma unroll 4
    for (int k = 0; k < 16; ++k) {
        int i = t0 + k * 1024 + threadIdx.x;
        if (i < tot) {
            int b, rl, col; float val;
            if (i < nA) {
                int r = Arow[i]; b = r / ROWS_A; rl = r - b * ROWS_A;
                col = Acol[i]; val = Aval[i];
            } else {
                int j = i - nA; int r = Xrow[j]; int bx = r / ROWS_X;
                b = nbA + bx; rl = r - bx * ROWS_X;
                col = Xcol[j]; val = Xval[j];
            }
            int pos = rbase[b] + atomicAdd(&cnt[b], 1);
            ebuf[pos] = make_uint2(((unsigned)rl << 25) | (unsigned)col, __float_as_uint(val));
        }
    }
}

// ---------------------------------------------------------------------------
// Prep: weight matrices -> (l, l+64)-paired float2 layout; emb -> packed bf16.
// Wtp[k*64 + l] = (W[l][k], W[l+64][k]);  P_emb[v*64 + l] = bf16(e[l], e[l+64]).
// ---------------------------------------------------------------------------
__global__ void prep_kernel(const float* __restrict__ W1, const float* __restrict__ W2,
                            const float* __restrict__ W3,
                            float2* __restrict__ Wt1, float2* __restrict__ Wt2,
                            float2* __restrict__ Wt3,
                            const float* __restrict__ emb, unsigned* __restrict__ P_emb,
                            int nemb) {   // nemb = V*64
    int gid = blockIdx.x * 256 + threadIdx.x;
    if (gid < 3 * 8192) {
        int m = gid >> 13;
        int idx = gid & 8191;
        int k = idx >> 6;
        int l = idx & 63;
        const float* W = (m == 0) ? W1 : (m == 1) ? W2 : W3;
        float2*     Wt = (m == 0) ? Wt1 : (m == 1) ? Wt2 : Wt3;
        Wt[k * 64 + l] = make_float2(W[l * 128 + k], W[(l + 64) * 128 + k]);
    }
    int e = gid - 3 * 8192;
    if (e >= 0 && e < nemb) {
        int v = e >> 6, l = e & 63;
        P_emb[e] = pack_bf16(emb[v * 128 + l], emb[v * 128 + l + 64]);
    }
}

// ---------------------------------------------------------------------------
// Fused bucket kernel: one block owns one bucket of ROWS rows.
// Edge phase: 8 waves stream the bucket's edge run (wave-uniform 8 B record
// loads, x4 unrolled 256 B gathers), ds_add_f32 into the LDS row tile
// (bank = lane%32 -> conflict-free). GEMM phase: wave w computes ROWS/8 rows.
//   MODE 0: P_out = bf16(relu(spmm @ W^T))
//   MODE 1: + residual(0.3 emb) + layernorm*g+b + emb  (word_H + emb pre-fused)
//   MODE 2: doc head: relu(spmm @ mlp^T + mb) -> 2-logit classifier
// ---------------------------------------------------------------------------
template <int ROWS, int MODE>
__global__ __launch_bounds__(512) void bucket_kernel(
    const int* __restrict__ boff, const uint2* __restrict__ ebuf, int bucket0,
    const unsigned* __restrict__ P_in, const float2* __restrict__ Wtp,
    const float* __restrict__ emb,            // MODE 1: fp32 emb  | MODE 2: mlp_b
    const float* __restrict__ g, const float* __restrict__ bb,  // MODE 1: LN | MODE 2: clfW, clfb
    unsigned* __restrict__ P_out,             // MODE 0/1 out | MODE 2: float* logits
    int nrows) {

    __shared__ float acc[ROWS][128];
    int lane = threadIdx.x & 63;
    int w = threadIdx.x >> 6;                 // 8 waves
    int rowbase = blockIdx.x * ROWS;

    for (int t = threadIdx.x; t < ROWS * 128; t += 512) ((float*)acc)[t] = 0.f;
    __syncthreads();

    // --- edge phase ---
    int b = bucket0 + blockIdx.x;
    int s = boff[b], e = boff[b + 1];
    int cnt = e - s;
    int chunk = (cnt + 7) >> 3;
    int cs = s + w * chunk;
    int ce = min(cs + chunk, e);
    int i = cs;
    for (; i + 3 < ce; i += 4) {
        uint2 r0 = ebuf[i], r1 = ebuf[i + 1], r2 = ebuf[i + 2], r3 = ebuf[i + 3];
        unsigned x0 = P_in[(size_t)(r0.x & 0x1FFFFFFu) * 64 + lane];
        unsigned x1 = P_in[(size_t)(r1.x & 0x1FFFFFFu) * 64 + lane];
        unsigned x2 = P_in[(size_t)(r2.x & 0x1FFFFFFu) * 64 + lane];
        unsigned x3 = P_in[(size_t)(r3.x & 0x1FFFFFFu) * 64 + lane];
        float v0 = __uint_as_float(r0.y), v1 = __uint_as_float(r1.y);
        float v2 = __uint_as_float(r2.y), v3 = __uint_as_float(r3.y);
        int rl0 = r0.x >> 25, rl1 = r1.x >> 25, rl2 = r2.x >> 25, rl3 = r3.x >> 25;
        atomicAdd(&acc[rl0][lane],      v0 * blo(x0));
        atomicAdd(&acc[rl0][lane + 64], v0 * bhi(x0));
        atomicAdd(&acc[rl1][lane],      v1 * blo(x1));
        atomicAdd(&acc[rl1][lane + 64], v1 * bhi(x1));
        atomicAdd(&acc[rl2][lane],      v2 * blo(x2));
        atomicAdd(&acc[rl2][lane + 64], v2 * bhi(x2));
        atomicAdd(&acc[rl3][lane],      v3 * blo(x3));
        atomicAdd(&acc[rl3][lane + 64], v3 * bhi(x3));
    }
    for (; i < ce; ++i) {
        uint2 r0 = ebuf[i];
        unsigned x0 = P_in[(size_t)(r0.x & 0x1FFFFFFu) * 64 + lane];
        float v0 = __uint_as_float(r0.y);
        int rl0 = r0.x >> 25;
        atomicAdd(&acc[rl0][lane],      v0 * blo(x0));
        atomicAdd(&acc[rl0][lane + 64], v0 * bhi(x0));
    }
    __syncthreads();

    // --- GEMM: o[r] = acc_row @ W^T, lane holds cols (lane, lane+64) ---
    const int RW = ROWS / 8;
    float2 o[RW];
    #pragma unroll
    for (int r = 0; r < RW; ++r) o[r] = make_float2(0.f, 0.f);
    for (int k = 0; k < 128; k += 2) {
        float2 w0 = Wtp[k * 64 + lane];
        float2 w1 = Wtp[(k + 1) * 64 + lane];
        #pragma unroll
        for (int r = 0; r < RW; ++r) {
            float a0 = acc[w * RW + r][k];
            float a1 = acc[w * RW + r][k + 1];
            o[r].x += a0 * w0.x + a1 * w1.x;
            o[r].y += a0 * w0.y + a1 * w1.y;
        }
    }

    // --- epilogue ---
    for (int r = 0; r < RW; ++r) {
        int row = rowbase + w * RW + r;
        if (row >= nrows) break;
        float hx = fmaxf(o[r].x, 0.f), hy = fmaxf(o[r].y, 0.f);
        if (MODE == 0) {
            P_out[(size_t)row * 64 + lane] = pack_bf16(hx, hy);
        } else if (MODE == 1) {
            float el = emb[(size_t)row * 128 + lane];
            float eh = emb[(size_t)row * 128 + lane + 64];
            float ux = 0.3f * el + 0.7f * hx;
            float uy = 0.3f * eh + 0.7f * hy;
            float sm = ux + uy;
            #pragma unroll
            for (int d = 1; d < 64; d <<= 1) sm += __shfl_xor(sm, d);
            float mu = sm * (1.f / 128.f);
            float dx = ux - mu, dy = uy - mu;
            float qv = dx * dx + dy * dy;
            #pragma unroll
            for (int d = 1; d < 64; d <<= 1) qv += __shfl_xor(qv, d);
            float rstd = rsqrtf(qv * (1.f / 128.f) + 1e-5f);
            float wx = dx * rstd * g[lane] + bb[lane] + el;           // +emb fused
            float wy = dy * rstd * g[lane + 64] + bb[lane + 64] + eh;
            P_out[(size_t)row * 64 + lane] = pack_bf16(wx, wy);
        } else {
            // MODE 2: emb = mlp_b, g = clfW [2][128], bb = clfb, P_out = float* logits
            float hx2 = fmaxf(o[r].x + emb[lane], 0.f);
            float hy2 = fmaxf(o[r].y + emb[lane + 64], 0.f);
            float p0 = hx2 * g[lane] + hy2 * g[lane + 64];
            float p1 = hx2 * g[128 + lane] + hy2 * g[128 + lane + 64];
            #pragma unroll
            for (int d = 1; d < 64; d <<= 1) {
                p0 += __shfl_xor(p0, d);
                p1 += __shfl_xor(p1, d);
            }
            if (lane == 0) {
                float* outp = (float*)P_out;
                outp[(size_t)row * 2 + 0] = p0 + bb[0];
                outp[(size_t)row * 2 + 1] = p1 + bb[1];
            }
        }
    }
}

// ---------------------------------------------------------------------------
extern "C" void kernel_launch(void* const* d_in, const int* in_sizes, int n_in,
                              void* d_out, int out_size, void* d_ws, size_t ws_size,
                              hipStream_t stream) {
    const int*   A_row  = (const int*)d_in[0];
    const int*   A_col  = (const int*)d_in[1];
    const float* A_val  = (const float*)d_in[2];
    const int*   X_row  = (const int*)d_in[3];
    const int*   X_col  = (const int*)d_in[4];
    const float* X_val  = (const float*)d_in[5];
    const float* emb_W  = (const float*)d_in[6];
    const float* lin1_W = (const float*)d_in[7];
    const float* lin2_W = (const float*)d_in[8];
    const float* norm_g = (const float*)d_in[9];
    const float* norm_b = (const float*)d_in[10];
    const float* mlp_W  = (const float*)d_in[11];
    const float* mlp_b  = (const float*)d_in[12];
    const float* clf_W  = (const float*)d_in[13];
    const float* clf_b  = (const float*)d_in[14];

    const int E   = in_sizes[0];
    const int NNZ = in_sizes[3];
    const int V   = in_sizes[6] / 128;
    const int D   = out_size / 2;   // N_DOCS
    const int nbA = (V + ROWS_A - 1) / ROWS_A;
    const int nbX = (D + ROWS_X - 1) / ROWS_X;
    const int nb  = nbA + nbX;      // 521 + 313 = 834 <= NB_MAX
    const int tot = E + NNZ;

    // workspace carve-up (256B aligned)
    char* p = (char*)d_ws;
    auto alloc = [&](size_t bytes) -> void* {
        void* q = (void*)p;
        p += (bytes + 255) & ~(size_t)255;
        return q;
    };
    int*      gcnt  = (int*)alloc((size_t)nb * 4);
    int*      boff  = (int*)alloc((size_t)(nb + 1) * 4);
    int*      gcur  = (int*)alloc((size_t)nb * 4);
    uint2*    ebuf  = (uint2*)alloc((size_t)tot * 8);
    float2*   Wt1   = (float2*)alloc(128 * 64 * 8);
    float2*   Wt2   = (float2*)alloc(128 * 64 * 8);
    float2*   Wt3   = (float2*)alloc(128 * 64 * 8);
    unsigned* P_EMB = (unsigned*)alloc((size_t)V * 64 * 4);
    unsigned* P_H1  = (unsigned*)alloc((size_t)V * 64 * 4);
    unsigned* P_WS  = (unsigned*)alloc((size_t)V * 64 * 4);

    hipMemsetAsync(gcnt, 0, (size_t)nb * 4, stream);

    hist_kernel<<<512, 256, 0, stream>>>(A_row, E, X_row, NNZ, nbA, nb, gcnt);
    scan_kernel<<<1, 1024, 0, stream>>>(gcnt, boff, gcur, nb);
    partition_kernel<<<(tot + TILE_EDGES - 1) / TILE_EDGES, 1024, 0, stream>>>(
        A_row, A_col, A_val, E, X_row, X_col, X_val, NNZ, nbA, nb, gcur, ebuf);
    prep_kernel<<<(3 * 8192 + V * 64 + 255) / 256, 256, 0, stream>>>(
        lin1_W, lin2_W, mlp_W, Wt1, Wt2, Wt3, emb_W, P_EMB, V * 64);

    bucket_kernel<ROWS_A, 0><<<nbA, 512, 0, stream>>>(
        boff, ebuf, 0, P_EMB, Wt1, nullptr, nullptr, nullptr, P_H1, V);
    bucket_kernel<ROWS_A, 1><<<nbA, 512, 0, stream>>>(
        boff, ebuf, 0, P_H1, Wt2, emb_W, norm_g, norm_b, P_WS, V);
    bucket_kernel<ROWS_X, 2><<<nbX, 512, 0, stream>>>(
        boff, ebuf, nbA, P_WS, Wt3, mlp_b, clf_W, clf_b, (unsigned*)d_out, D);
}

// Round 5
// 962.777 us; speedup vs baseline: 5.2039x; 5.2039x over previous
//
#include <hip/hip_runtime.h>

#define NB_MAX 1024       // LDS counter capacity in partition kernel
#define RA 196            // rows per A-bucket  (256 buckets for V=50000)
#define RX 79             // rows per X-bucket  (254 buckets for D=20000)
#define PT_THREADS 512
#define PT_EPT 16         // edges per thread per partition tile
#define TILE_EDGES (PT_THREADS * PT_EPT)

// ---- bf16 helpers: table uint at [row][l] packs cols (2l, 2l+1) ------------
__device__ __forceinline__ float blo(unsigned u) { return __uint_as_float(u << 16); }
__device__ __forceinline__ float bhi(unsigned u) { return __uint_as_float(u & 0xffff0000u); }
__device__ __forceinline__ unsigned pack_bf16(float x, float y) {
    unsigned ux = __float_as_uint(x); ux += 0x7fffu + ((ux >> 16) & 1u);
    unsigned uy = __float_as_uint(y); uy += 0x7fffu + ((uy >> 16) & 1u);
    return (ux >> 16) | (uy & 0xffff0000u);
}

// ---------------------------------------------------------------------------
// Row-level histogram (global atomics; counters are L2-resident).
// ---------------------------------------------------------------------------
__global__ void hist_kernel(const int* __restrict__ Arow, int nA,
                            const int* __restrict__ Xrow, int nX,
                            int* __restrict__ cntA, int* __restrict__ cntX) {
    int i = blockIdx.x * 256 + threadIdx.x;
    if (i < nA) {
        atomicAdd(&cntA[Arow[i]], 1);
    } else if (i < nA + nX) {
        atomicAdd(&cntX[Xrow[i - nA]], 1);
    }
}

// ---------------------------------------------------------------------------
// Hierarchical scan stage 1: block-local scan of 1024-row chunks.
// off[i+1] = local inclusive, cnt[i] = local exclusive, chunkSums[b] = total.
// ---------------------------------------------------------------------------
__global__ __launch_bounds__(1024) void scan1_kernel(
    int* cntA, int* offA, int nA, int nchA,
    int* cntX, int* offX, int nX, int* chunkSums) {
    int b = blockIdx.x;
    int* cnt; int* off; int n; int cb;
    if (b < nchA) { cnt = cntA; off = offA; n = nA; cb = b; }
    else          { cnt = cntX; off = offX; n = nX; cb = b - nchA; }
    __shared__ int wsum[16];
    int tid = threadIdx.x, lane = tid & 63, w = tid >> 6;
    int i = cb * 1024 + tid;
    int x = (i < n) ? cnt[i] : 0;
    int v = x;
    #pragma unroll
    for (int d = 1; d < 64; d <<= 1) {
        int t = __shfl_up(v, d);
        if (lane >= d) v += t;
    }
    if (lane == 63) wsum[w] = v;
    __syncthreads();
    if (tid == 0) {
        int a = 0;
        #pragma unroll
        for (int j = 0; j < 16; ++j) { int t = wsum[j]; wsum[j] = a; a += t; }
        chunkSums[b] = a;
    }
    __syncthreads();
    int incl = v + wsum[w];
    if (i < n) { off[i + 1] = incl; cnt[i] = incl - x; }
}

// ---------------------------------------------------------------------------
// Stage 2: exclusive-scan chunk totals (wave 0: A chunks, wave 1: X chunks).
// ---------------------------------------------------------------------------
__global__ __launch_bounds__(128) void scan2_kernel(int* chunkSums, int nchA, int nchX) {
    int lane = threadIdx.x & 63;
    int w = threadIdx.x >> 6;
    int n    = (w == 0) ? nchA : nchX;
    int base = (w == 0) ? 0 : nchA;
    int carry = 0;
    for (int s = 0; s < n; s += 64) {
        int v = (s + lane < n) ? chunkSums[base + s + lane] : 0;
        int incl = v;
        #pragma unroll
        for (int d = 1; d < 64; d <<= 1) {
            int t = __shfl_up(incl, d);
            if (lane >= d) incl += t;
        }
        int tot = __shfl(incl, 63);
        int ex = __shfl_up(incl, 1);
        if (lane == 0) ex = 0;
        if (s + lane < n) chunkSums[base + s + lane] = carry + ex;
        carry += tot;
    }
}

// ---------------------------------------------------------------------------
// Stage 3: add chunk bases -> global row offsets + row cursors; off[0]=0.
// ---------------------------------------------------------------------------
__global__ void scan3_kernel(int* cntA, int* offA, int nA, int nchA,
                             int* cntX, int* offX, int nX,
                             const int* __restrict__ chunkSums) {
    int i = blockIdx.x * 256 + threadIdx.x;
    if (i < nA) {
        int b = chunkSums[i >> 10];
        cntA[i] += b; offA[i + 1] += b;
        if (i == 0) offA[0] = 0;
    } else {
        int j = i - nA;
        if (j < nX) {
            int b = chunkSums[nchA + (j >> 10)];
            cntX[j] += b; offX[j + 1] += b;
            if (j == 0) offX[0] = 0;
        }
    }
}

// ---------------------------------------------------------------------------
// Bucket cursors from row offsets (free: bucket start = off[first row]).
// A buckets [0,nbA) -> ebuf [0,E); X buckets -> ebuf [E, E+NNZ).
// ---------------------------------------------------------------------------
__global__ void initg_kernel(const int* __restrict__ offA, const int* __restrict__ offX,
                             int* __restrict__ gcur, int nbA, int nb, int V, int D, int E) {
    int b = blockIdx.x * 256 + threadIdx.x;
    if (b < nbA)      gcur[b] = offA[min(b * RA, V)];
    else if (b < nb)  gcur[b] = E + offX[min((b - nbA) * RX, D)];
}

// ---------------------------------------------------------------------------
// Partition edges into bucket-major ebuf with per-tile run reservation:
// count tile in LDS -> one atomicAdd per touched bucket reserves a contiguous
// run -> re-read, write into run. Writes are coalesced runs at ~nb fronts.
// Record: x = (row_local << 17) | col, y = bits(val).
// ---------------------------------------------------------------------------
__global__ __launch_bounds__(PT_THREADS) void partition_kernel(
    const int* __restrict__ Arow, const int* __restrict__ Acol, const float* __restrict__ Aval, int nA,
    const int* __restrict__ Xrow, const int* __restrict__ Xcol, const float* __restrict__ Xval, int nX,
    int nbA, int nb, int* __restrict__ gcur, uint2* __restrict__ ebuf) {
    __shared__ int cnt[NB_MAX];
    __shared__ int rbase[NB_MAX];
    for (int t = threadIdx.x; t < nb; t += PT_THREADS) cnt[t] = 0;
    __syncthreads();
    int tot = nA + nX;
    int t0 = blockIdx.x * TILE_EDGES;
    #pragma unroll 4
    for (int k = 0; k < PT_EPT; ++k) {
        int i = t0 + k * PT_THREADS + threadIdx.x;
        if (i < tot) {
            int b = (i < nA) ? (Arow[i] / RA) : (nbA + Xrow[i - nA] / RX);
            atomicAdd(&cnt[b], 1);
        }
    }
    __syncthreads();
    for (int t = threadIdx.x; t < nb; t += PT_THREADS) {
        int c = cnt[t];
        rbase[t] = c ? atomicAdd(&gcur[t], c) : 0;
        cnt[t] = 0;
    }
    __syncthreads();
    #pragma unroll 4
    for (int k = 0; k < PT_EPT; ++k) {
        int i = t0 + k * PT_THREADS + threadIdx.x;
        if (i < tot) {
            int b, rl, col; float val;
            if (i < nA) {
                int r = Arow[i]; b = r / RA; rl = r - b * RA;
                col = Acol[i]; val = Aval[i];
            } else {
                int j = i - nA; int r = Xrow[j]; int bx = r / RX;
                b = nbA + bx; rl = r - bx * RX;
                col = Xcol[j]; val = Xval[j];
            }
            int pos = rbase[b] + atomicAdd(&cnt[b], 1);
            ebuf[pos] = make_uint2(((unsigned)rl << 17) | (unsigned)col, __float_as_uint(val));
        }
    }
}

// ---------------------------------------------------------------------------
// Cluster: one block per bucket; scatter bucket edges to exact CSR position.
// Write window is the bucket's CSR span (~50-100 KB) -> L2-merged writebacks.
// Row cursors are block-private (each row belongs to exactly one bucket).
// ---------------------------------------------------------------------------
__global__ __launch_bounds__(256) void cluster_kernel(
    const uint2* __restrict__ ebuf,
    const int* __restrict__ offA, const int* __restrict__ offX,
    int* __restrict__ curA, int* __restrict__ curX,
    int2* __restrict__ csrA, int2* __restrict__ csrX,
    int nbA, int V, int D, int E) {
    int b = blockIdx.x;
    int r0, s, e; int* cur; int2* csr;
    if (b < nbA) {
        r0 = b * RA;
        s = offA[r0]; e = offA[min(r0 + RA, V)];
        cur = curA; csr = csrA;
    } else {
        int j = b - nbA;
        r0 = j * RX;
        s = E + offX[r0]; e = E + offX[min(r0 + RX, D)];
        cur = curX; csr = csrX;
    }
    for (int i = s + threadIdx.x; i < e; i += 256) {
        uint2 rec = ebuf[i];
        int row = r0 + (rec.x >> 17);
        int p = atomicAdd(&cur[row], 1);
        csr[p] = make_int2(rec.x & 0x1FFFF, (int)rec.y);
    }
}

// ---------------------------------------------------------------------------
// Prep: transpose 128x128 weights (Wt[k][j] = W[j][k]) + emb -> packed bf16.
// ---------------------------------------------------------------------------
__global__ void prep_kernel(const float* __restrict__ W1, const float* __restrict__ W2,
                            const float* __restrict__ W3,
                            float* __restrict__ Wt1, float* __restrict__ Wt2,
                            float* __restrict__ Wt3,
                            const float2* __restrict__ emb, unsigned* __restrict__ emb16,
                            int nemb) {   // nemb = V*64
    int gid = blockIdx.x * 256 + threadIdx.x;
    if (gid < 3 * 16384) {
        int m = gid >> 14;
        int idx = gid & 16383;
        int j = idx >> 7;
        int k = idx & 127;
        const float* W = (m == 0) ? W1 : (m == 1) ? W2 : W3;
        float*      Wt = (m == 0) ? Wt1 : (m == 1) ? Wt2 : Wt3;
        Wt[k * 128 + j] = W[j * 128 + k];
    }
    int e = gid - 3 * 16384;
    if (e >= 0 && e < nemb) {
        float2 f = emb[e];
        emb16[e] = pack_bf16(f.x, f.y);
    }
}

// ---------------------------------------------------------------------------
// Fused layer kernel (R2 structure). One wave owns R rows; lane l holds cols
// 2l, 2l+1. Wave-uniform int2 record loads, x4-unrolled 256 B gathers.
//   mode 0: out = bf16(relu(spmm(A,in) @ W^T))
//   mode 1: t = relu(spmm(A,in) @ W^T); u = 0.3*emb + 0.7*t;
//           out = bf16(layernorm(u)*g + b + emb)   (word_H + emb_W pre-fused)
// ---------------------------------------------------------------------------
template <int R>
__global__ __launch_bounds__(256) void layer_kernel(
    const int* __restrict__ off, const int2* __restrict__ csr,
    const unsigned* __restrict__ in,          // bf16-packed [nrows][64]
    const float2* __restrict__ Wt,            // [128][64] float2 view
    const float2* __restrict__ emb,           // fp32, mode 1 only
    const float* __restrict__ g, const float* __restrict__ bb,  // mode 1 only
    unsigned* __restrict__ out, int nrows, int mode) {

    __shared__ float acc_s[4][R][128];
    int lane = threadIdx.x & 63;
    int wave = threadIdx.x >> 6;
    int rowbase = (blockIdx.x * 4 + wave) * R;

    // --- SpMM into wave-private LDS ---
    for (int r = 0; r < R; ++r) {
        int row = rowbase + r;
        float ax = 0.f, ay = 0.f;
        if (row < nrows) {
            int s = off[row], e = off[row + 1];
            int i = s;
            for (; i + 3 < e; i += 4) {
                int2 c0 = csr[i], c1 = csr[i + 1], c2 = csr[i + 2], c3 = csr[i + 3];
                unsigned x0 = in[(size_t)c0.x * 64 + lane];
                unsigned x1 = in[(size_t)c1.x * 64 + lane];
                unsigned x2 = in[(size_t)c2.x * 64 + lane];
                unsigned x3 = in[(size_t)c3.x * 64 + lane];
                float v0 = __int_as_float(c0.y), v1 = __int_as_float(c1.y);
                float v2 = __int_as_float(c2.y), v3 = __int_as_float(c3.y);
                ax += v0 * blo(x0) + v1 * blo(x1) + v2 * blo(x2) + v3 * blo(x3);
                ay += v0 * bhi(x0) + v1 * bhi(x1) + v2 * bhi(x2) + v3 * bhi(x3);
            }
            for (; i < e; ++i) {
                int2 cv = csr[i];
                unsigned x = in[(size_t)cv.x * 64 + lane];
                float v = __int_as_float(cv.y);
                ax += v * blo(x);
                ay += v * bhi(x);
            }
        }
        *(float2*)&acc_s[wave][r][2 * lane] = make_float2(ax, ay);
    }

    // --- dense 128x128 GEMM: o[r][j] = sum_k acc[r][k] * Wt[k][j] ---
    float2 o[R];
    #pragma unroll
    for (int r = 0; r < R; ++r) o[r] = make_float2(0.f, 0.f);
    for (int k = 0; k < 128; k += 2) {
        float2 w0 = Wt[(size_t)k * 64 + lane];
        float2 w1 = Wt[(size_t)(k + 1) * 64 + lane];
        #pragma unroll
        for (int r = 0; r < R; ++r) {
            float b0 = acc_s[wave][r][k];
            float b1 = acc_s[wave][r][k + 1];
            o[r].x += b0 * w0.x + b1 * w1.x;
            o[r].y += b0 * w0.y + b1 * w1.y;
        }
    }

    // --- epilogue ---
    for (int r = 0; r < R; ++r) {
        int row = rowbase + r;
        if (row >= nrows) break;
        float hx = fmaxf(o[r].x, 0.f), hy = fmaxf(o[r].y, 0.f);
        if (mode == 0) {
            out[(size_t)row * 64 + lane] = pack_bf16(hx, hy);
        } else {
            float2 e2 = emb[(size_t)row * 64 + lane];
            float ux = 0.3f * e2.x + 0.7f * hx;
            float uy = 0.3f * e2.y + 0.7f * hy;
            float s = ux + uy;
            #pragma unroll
            for (int d = 1; d < 64; d <<= 1) s += __shfl_xor(s, d);
            float mu = s * (1.f / 128.f);
            float dx = ux - mu, dy = uy - mu;
            float qv = dx * dx + dy * dy;
            #pragma unroll
            for (int d = 1; d < 64; d <<= 1) qv += __shfl_xor(qv, d);
            float rstd = rsqrtf(qv * (1.f / 128.f) + 1e-5f);
            float2 gg = *(const float2*)&g[2 * lane];
            float2 b2 = *(const float2*)&bb[2 * lane];
            float wx = dx * rstd * gg.x + b2.x + e2.x;   // word_H + emb_W fused
            float wy = dy * rstd * gg.y + b2.y + e2.y;
            out[(size_t)row * 64 + lane] = pack_bf16(wx, wy);
        }
    }
}

// ---------------------------------------------------------------------------
// Doc kernel: spmm(X, word_sum[bf16]) -> relu(. @ mlp_W^T + b) -> clf logits.
// ---------------------------------------------------------------------------
template <int R>
__global__ __launch_bounds__(256) void doc_kernel(
    const int* __restrict__ off, const int2* __restrict__ csr,
    const unsigned* __restrict__ in,          // bf16-packed word_sum [V][64]
    const float2* __restrict__ Wt,            // mlp_W transposed, float2 view
    const float* __restrict__ mlp_b, const float* __restrict__ clfW,
    const float* __restrict__ clfb,
    float* __restrict__ outp, int nrows) {

    __shared__ float acc_s[4][R][128];
    int lane = threadIdx.x & 63;
    int wave = threadIdx.x >> 6;
    int rowbase = (blockIdx.x * 4 + wave) * R;

    for (int r = 0; r < R; ++r) {
        int row = rowbase + r;
        float ax = 0.f, ay = 0.f;
        if (row < nrows) {
            int s = off[row], e = off[row + 1];
            int i = s;
            for (; i + 3 < e; i += 4) {
                int2 c0 = csr[i], c1 = csr[i + 1], c2 = csr[i + 2], c3 = csr[i + 3];
                unsigned x0 = in[(size_t)c0.x * 64 + lane];
                unsigned x1 = in[(size_t)c1.x * 64 + lane];
                unsigned x2 = in[(size_t)c2.x * 64 + lane];
                unsigned x3 = in[(size_t)c3.x * 64 + lane];
                float v0 = __int_as_float(c0.y), v1 = __int_as_float(c1.y);
                float v2 = __int_as_float(c2.y), v3 = __int_as_float(c3.y);
                ax += v0 * blo(x0) + v1 * blo(x1) + v2 * blo(x2) + v3 * blo(x3);
                ay += v0 * bhi(x0) + v1 * bhi(x1) + v2 * bhi(x2) + v3 * bhi(x3);
            }
            for (; i < e; ++i) {
                int2 cv = csr[i];
                unsigned x = in[(size_t)cv.x * 64 + lane];
                float v = __int_as_float(cv.y);
                ax += v * blo(x);
                ay += v * bhi(x);
            }
        }
        *(float2*)&acc_s[wave][r][2 * lane] = make_float2(ax, ay);
    }

    float2 o[R];
    #pragma unroll
    for (int r = 0; r < R; ++r) o[r] = make_float2(0.f, 0.f);
    for (int k = 0; k < 128; k += 2) {
        float2 w0 = Wt[(size_t)k * 64 + lane];
        float2 w1 = Wt[(size_t)(k + 1) * 64 + lane];
        #pragma unroll
        for (int r = 0; r < R; ++r) {
            float b0 = acc_s[wave][r][k];
            float b1 = acc_s[wave][r][k + 1];
            o[r].x += b0 * w0.x + b1 * w1.x;
            o[r].y += b0 * w0.y + b1 * w1.y;
        }
    }

    float2 mb = *(const float2*)&mlp_b[2 * lane];
    float2 c0 = *(const float2*)&clfW[2 * lane];
    float2 c1 = *(const float2*)&clfW[128 + 2 * lane];
    for (int r = 0; r < R; ++r) {
        int row = rowbase + r;
        if (row >= nrows) break;
        float hx = fmaxf(o[r].x + mb.x, 0.f);
        float hy = fmaxf(o[r].y + mb.y, 0.f);
        float p0 = hx * c0.x + hy * c0.y;
        float p1 = hx * c1.x + hy * c1.y;
        #pragma unroll
        for (int d = 1; d < 64; d <<= 1) {
            p0 += __shfl_xor(p0, d);
            p1 += __shfl_xor(p1, d);
        }
        if (lane == 0) {
            outp[(size_t)row * 2 + 0] = p0 + clfb[0];
            outp[(size_t)row * 2 + 1] = p1 + clfb[1];
        }
    }
}

// ---------------------------------------------------------------------------
extern "C" void kernel_launch(void* const* d_in, const int* in_sizes, int n_in,
                              void* d_out, int out_size, void* d_ws, size_t ws_size,
                              hipStream_t stream) {
    const int*   A_row  = (const int*)d_in[0];
    const int*   A_col  = (const int*)d_in[1];
    const float* A_val  = (const float*)d_in[2];
    const int*   X_row  = (const int*)d_in[3];
    const int*   X_col  = (const int*)d_in[4];
    const float* X_val  = (const float*)d_in[5];
    const float* emb_W  = (const float*)d_in[6];
    const float* lin1_W = (const float*)d_in[7];
    const float* lin2_W = (const float*)d_in[8];
    const float* norm_g = (const float*)d_in[9];
    const float* norm_b = (const float*)d_in[10];
    const float* mlp_W  = (const float*)d_in[11];
    const float* mlp_b  = (const float*)d_in[12];
    const float* clf_W  = (const float*)d_in[13];
    const float* clf_b  = (const float*)d_in[14];

    const int E   = in_sizes[0];
    const int NNZ = in_sizes[3];
    const int V   = in_sizes[6] / 128;
    const int D   = out_size / 2;   // N_DOCS
    const int tot = E + NNZ;
    const int nchA = (V + 1023) / 1024;
    const int nchX = (D + 1023) / 1024;
    const int nbA = (V + RA - 1) / RA;   // 256
    const int nbX = (D + RX - 1) / RX;   // 254
    const int nb  = nbA + nbX;           // 510 <= NB_MAX

    // workspace carve-up (256B aligned)
    char* p = (char*)d_ws;
    auto alloc = [&](size_t bytes) -> void* {
        void* q = (void*)p;
        p += (bytes + 255) & ~(size_t)255;
        return q;
    };
    int*      curA   = (int*)alloc((size_t)V * 4);
    int*      offA   = (int*)alloc((size_t)(V + 1) * 4);
    int*      curX   = (int*)alloc((size_t)D * 4);
    int*      offX   = (int*)alloc((size_t)(D + 1) * 4);
    int*      chunkS = (int*)alloc((size_t)(nchA + nchX) * 4);
    int*      gcur   = (int*)alloc((size_t)nb * 4);
    int2*     csrA   = (int2*)alloc((size_t)E * 8);
    int2*     csrX   = (int2*)alloc((size_t)NNZ * 8);
    float*    Wt1    = (float*)alloc(128 * 128 * 4);
    float*    Wt2    = (float*)alloc(128 * 128 * 4);
    float*    Wt3    = (float*)alloc(128 * 128 * 4);
    unsigned* P_EMB  = (unsigned*)alloc((size_t)V * 64 * 4);
    // ebuf is dead after cluster_kernel; H1/WS alias it (stream-ordered).
    char*     ebuf_region = (char*)alloc((size_t)tot * 8 > 2 * (size_t)V * 64 * 4
                                         ? (size_t)tot * 8 : 2 * (size_t)V * 64 * 4);
    uint2*    ebuf  = (uint2*)ebuf_region;
    unsigned* P_H1  = (unsigned*)ebuf_region;
    unsigned* P_WS  = (unsigned*)(ebuf_region + (size_t)V * 64 * 4);

    hipMemsetAsync(curA, 0, (size_t)V * 4, stream);
    hipMemsetAsync(curX, 0, (size_t)D * 4, stream);

    hist_kernel<<<(tot + 255) / 256, 256, 0, stream>>>(A_row, E, X_row, NNZ, curA, curX);
    scan1_kernel<<<nchA + nchX, 1024, 0, stream>>>(curA, offA, V, nchA, curX, offX, D, chunkS);
    scan2_kernel<<<1, 128, 0, stream>>>(chunkS, nchA, nchX);
    scan3_kernel<<<(V + D + 255) / 256, 256, 0, stream>>>(curA, offA, V, nchA, curX, offX, D, chunkS);
    initg_kernel<<<(nb + 255) / 256, 256, 0, stream>>>(offA, offX, gcur, nbA, nb, V, D, E);
    partition_kernel<<<(tot + TILE_EDGES - 1) / TILE_EDGES, PT_THREADS, 0, stream>>>(
        A_row, A_col, A_val, E, X_row, X_col, X_val, NNZ, nbA, nb, gcur, ebuf);
    cluster_kernel<<<nb, 256, 0, stream>>>(
        ebuf, offA, offX, curA, curX, csrA, csrX, nbA, V, D, E);
    prep_kernel<<<(3 * 16384 + V * 64 + 255) / 256, 256, 0, stream>>>(
        lin1_W, lin2_W, mlp_W, Wt1, Wt2, Wt3, (const float2*)emb_W, P_EMB, V * 64);

    int layer_blocks = (V + 4 * 4 - 1) / (4 * 4);
    layer_kernel<4><<<layer_blocks, 256, 0, stream>>>(
        offA, csrA, P_EMB, (const float2*)Wt1,
        nullptr, nullptr, nullptr, P_H1, V, 0);
    layer_kernel<4><<<layer_blocks, 256, 0, stream>>>(
        offA, csrA, P_H1, (const float2*)Wt2,
        (const float2*)emb_W, norm_g, norm_b, P_WS, V, 1);

    int doc_blocks = (D + 4 * 2 - 1) / (4 * 2);
    doc_kernel<2><<<doc_blocks, 256, 0, stream>>>(
        offX, csrX, P_WS, (const float2*)Wt3,
        mlp_b, clf_W, clf_b, (float*)d_out, D);
}

// Round 6
// 796.693 us; speedup vs baseline: 6.2888x; 1.2085x over previous
//
#include <hip/hip_runtime.h>

#define NB_MAX 1024       // LDS counter capacity in partition kernel
#define RA 196            // rows per A-bucket  (256 buckets for V=50000)
#define RX 79             // rows per X-bucket  (254 buckets for D=20000)
#define PT_THREADS 512
#define PT_EPT 16         // edges per thread per partition tile
#define TILE_EDGES (PT_THREADS * PT_EPT)

// ---- bf16 helpers: table uint at [row][l] packs cols (2l, 2l+1) ------------
__device__ __forceinline__ float blo(unsigned u) { return __uint_as_float(u << 16); }
__device__ __forceinline__ float bhi(unsigned u) { return __uint_as_float(u & 0xffff0000u); }
__device__ __forceinline__ unsigned pack_bf16(float x, float y) {
    unsigned ux = __float_as_uint(x); ux += 0x7fffu + ((ux >> 16) & 1u);
    unsigned uy = __float_as_uint(y); uy += 0x7fffu + ((uy >> 16) & 1u);
    return (ux >> 16) | (uy & 0xffff0000u);
}

// ---------------------------------------------------------------------------
// Row-level histogram (global atomics; counters are L2-resident).
// ---------------------------------------------------------------------------
__global__ void hist_kernel(const int* __restrict__ Arow, int nA,
                            const int* __restrict__ Xrow, int nX,
                            int* __restrict__ cntA, int* __restrict__ cntX) {
    int i = blockIdx.x * 256 + threadIdx.x;
    if (i < nA) {
        atomicAdd(&cntA[Arow[i]], 1);
    } else if (i < nA + nX) {
        atomicAdd(&cntX[Xrow[i - nA]], 1);
    }
}

// ---------------------------------------------------------------------------
// Hierarchical scan stage 1: block-local scan of 1024-row chunks.
// ---------------------------------------------------------------------------
__global__ __launch_bounds__(1024) void scan1_kernel(
    int* cntA, int* offA, int nA, int nchA,
    int* cntX, int* offX, int nX, int* chunkSums) {
    int b = blockIdx.x;
    int* cnt; int* off; int n; int cb;
    if (b < nchA) { cnt = cntA; off = offA; n = nA; cb = b; }
    else          { cnt = cntX; off = offX; n = nX; cb = b - nchA; }
    __shared__ int wsum[16];
    int tid = threadIdx.x, lane = tid & 63, w = tid >> 6;
    int i = cb * 1024 + tid;
    int x = (i < n) ? cnt[i] : 0;
    int v = x;
    #pragma unroll
    for (int d = 1; d < 64; d <<= 1) {
        int t = __shfl_up(v, d);
        if (lane >= d) v += t;
    }
    if (lane == 63) wsum[w] = v;
    __syncthreads();
    if (tid == 0) {
        int a = 0;
        #pragma unroll
        for (int j = 0; j < 16; ++j) { int t = wsum[j]; wsum[j] = a; a += t; }
        chunkSums[b] = a;
    }
    __syncthreads();
    int incl = v + wsum[w];
    if (i < n) { off[i + 1] = incl; cnt[i] = incl - x; }
}

// ---------------------------------------------------------------------------
// Stage 2: exclusive-scan chunk totals (wave 0: A chunks, wave 1: X chunks).
// ---------------------------------------------------------------------------
__global__ __launch_bounds__(128) void scan2_kernel(int* chunkSums, int nchA, int nchX) {
    int lane = threadIdx.x & 63;
    int w = threadIdx.x >> 6;
    int n    = (w == 0) ? nchA : nchX;
    int base = (w == 0) ? 0 : nchA;
    int carry = 0;
    for (int s = 0; s < n; s += 64) {
        int v = (s + lane < n) ? chunkSums[base + s + lane] : 0;
        int incl = v;
        #pragma unroll
        for (int d = 1; d < 64; d <<= 1) {
            int t = __shfl_up(incl, d);
            if (lane >= d) incl += t;
        }
        int tot = __shfl(incl, 63);
        int ex = __shfl_up(incl, 1);
        if (lane == 0) ex = 0;
        if (s + lane < n) chunkSums[base + s + lane] = carry + ex;
        carry += tot;
    }
}

// ---------------------------------------------------------------------------
// Stage 3: add chunk bases -> global row offsets + row cursors; off[0]=0.
// ---------------------------------------------------------------------------
__global__ void scan3_kernel(int* cntA, int* offA, int nA, int nchA,
                             int* cntX, int* offX, int nX,
                             const int* __restrict__ chunkSums) {
    int i = blockIdx.x * 256 + threadIdx.x;
    if (i < nA) {
        int b = chunkSums[i >> 10];
        cntA[i] += b; offA[i + 1] += b;
        if (i == 0) offA[0] = 0;
    } else {
        int j = i - nA;
        if (j < nX) {
            int b = chunkSums[nchA + (j >> 10)];
            cntX[j] += b; offX[j + 1] += b;
            if (j == 0) offX[0] = 0;
        }
    }
}

// ---------------------------------------------------------------------------
// Bucket cursors from row offsets (free: bucket start = off[first row]).
// ---------------------------------------------------------------------------
__global__ void initg_kernel(const int* __restrict__ offA, const int* __restrict__ offX,
                             int* __restrict__ gcur, int nbA, int nb, int V, int D, int E) {
    int b = blockIdx.x * 256 + threadIdx.x;
    if (b < nbA)      gcur[b] = offA[min(b * RA, V)];
    else if (b < nb)  gcur[b] = E + offX[min((b - nbA) * RX, D)];
}

// ---------------------------------------------------------------------------
// Partition edges into bucket-major ebuf with per-tile run reservation.
// Record: x = (row_local << 17) | col, y = bits(val).
// ---------------------------------------------------------------------------
__global__ __launch_bounds__(PT_THREADS) void partition_kernel(
    const int* __restrict__ Arow, const int* __restrict__ Acol, const float* __restrict__ Aval, int nA,
    const int* __restrict__ Xrow, const int* __restrict__ Xcol, const float* __restrict__ Xval, int nX,
    int nbA, int nb, int* __restrict__ gcur, uint2* __restrict__ ebuf) {
    __shared__ int cnt[NB_MAX];
    __shared__ int rbase[NB_MAX];
    for (int t = threadIdx.x; t < nb; t += PT_THREADS) cnt[t] = 0;
    __syncthreads();
    int tot = nA + nX;
    int t0 = blockIdx.x * TILE_EDGES;
    #pragma unroll 4
    for (int k = 0; k < PT_EPT; ++k) {
        int i = t0 + k * PT_THREADS + threadIdx.x;
        if (i < tot) {
            int b = (i < nA) ? (Arow[i] / RA) : (nbA + Xrow[i - nA] / RX);
            atomicAdd(&cnt[b], 1);
        }
    }
    __syncthreads();
    for (int t = threadIdx.x; t < nb; t += PT_THREADS) {
        int c = cnt[t];
        rbase[t] = c ? atomicAdd(&gcur[t], c) : 0;
        cnt[t] = 0;
    }
    __syncthreads();
    #pragma unroll 4
    for (int k = 0; k < PT_EPT; ++k) {
        int i = t0 + k * PT_THREADS + threadIdx.x;
        if (i < tot) {
            int b, rl, col; float val;
            if (i < nA) {
                int r = Arow[i]; b = r / RA; rl = r - b * RA;
                col = Acol[i]; val = Aval[i];
            } else {
                int j = i - nA; int r = Xrow[j]; int bx = r / RX;
                b = nbA + bx; rl = r - bx * RX;
                col = Xcol[j]; val = Xval[j];
            }
            int pos = rbase[b] + atomicAdd(&cnt[b], 1);
            ebuf[pos] = make_uint2(((unsigned)rl << 17) | (unsigned)col, __float_as_uint(val));
        }
    }
}

// ---------------------------------------------------------------------------
// Cluster: one block per bucket; scatter bucket edges to exact CSR position.
// Random writes confined to the bucket's ~50-100 KB CSR span (L2-merged).
// ---------------------------------------------------------------------------
__global__ __launch_bounds__(256) void cluster_kernel(
    const uint2* __restrict__ ebuf,
    const int* __restrict__ offA, const int* __restrict__ offX,
    int* __restrict__ curA, int* __restrict__ curX,
    int2* __restrict__ csrA, int2* __restrict__ csrX,
    int nbA, int V, int D, int E) {
    int b = blockIdx.x;
    int r0, s, e; int* cur; int2* csr;
    if (b < nbA) {
        r0 = b * RA;
        s = offA[r0]; e = offA[min(r0 + RA, V)];
        cur = curA; csr = csrA;
    } else {
        int j = b - nbA;
        r0 = j * RX;
        s = E + offX[r0]; e = E + offX[min(r0 + RX, D)];
        cur = curX; csr = csrX;
    }
    for (int i = s + threadIdx.x; i < e; i += 256) {
        uint2 rec = ebuf[i];
        int row = r0 + (rec.x >> 17);
        int p = atomicAdd(&cur[row], 1);
        csr[p] = make_int2(rec.x & 0x1FFFF, (int)rec.y);
    }
}

// ---------------------------------------------------------------------------
// Prep: transpose 128x128 weights (Wt[k][j] = W[j][k]) + emb -> packed bf16.
// ---------------------------------------------------------------------------
__global__ void prep_kernel(const float* __restrict__ W1, const float* __restrict__ W2,
                            const float* __restrict__ W3,
                            float* __restrict__ Wt1, float* __restrict__ Wt2,
                            float* __restrict__ Wt3,
                            const float2* __restrict__ emb, unsigned* __restrict__ emb16,
                            int nemb) {   // nemb = V*64
    int gid = blockIdx.x * 256 + threadIdx.x;
    if (gid < 3 * 16384) {
        int m = gid >> 14;
        int idx = gid & 16383;
        int j = idx >> 7;
        int k = idx & 127;
        const float* W = (m == 0) ? W1 : (m == 1) ? W2 : W3;
        float*      Wt = (m == 0) ? Wt1 : (m == 1) ? Wt2 : Wt3;
        Wt[k * 128 + j] = W[j * 128 + k];
    }
    int e = gid - 3 * 16384;
    if (e >= 0 && e < nemb) {
        float2 f = emb[e];
        emb16[e] = pack_bf16(f.x, f.y);
    }
}

// ---------------------------------------------------------------------------
// Fused layer kernel. One wave owns R rows; lane l holds cols 2l, 2l+1.
// __launch_bounds__(256, 8): cap VGPR at 64 so 8 waves/SIMD fit — the R5
// build's 204-VGPR bloat (compiler mega-unroll) collapsed occupancy to 11%.
// #pragma unroll 1 on row/edge loops, unroll 4 on GEMM k-loop: same intent.
//   mode 0: out = bf16(relu(spmm(A,in) @ W^T))
//   mode 1: t = relu(spmm(A,in) @ W^T); u = 0.3*emb + 0.7*t;
//           out = bf16(layernorm(u)*g + b + emb)   (word_H + emb_W pre-fused)
// ---------------------------------------------------------------------------
template <int R>
__global__ __launch_bounds__(256, 8) void layer_kernel(
    const int* __restrict__ off, const int2* __restrict__ csr,
    const unsigned* __restrict__ in,          // bf16-packed [nrows][64]
    const float2* __restrict__ Wt,            // [128][64] float2 view
    const float2* __restrict__ emb,           // fp32, mode 1 only
    const float* __restrict__ g, const float* __restrict__ bb,  // mode 1 only
    unsigned* __restrict__ out, int nrows, int mode) {

    __shared__ float acc_s[4][R][128];
    int lane = threadIdx.x & 63;
    int wave = threadIdx.x >> 6;
    int rowbase = (blockIdx.x * 4 + wave) * R;

    // --- SpMM into wave-private LDS ---
    #pragma unroll 1
    for (int r = 0; r < R; ++r) {
        int row = rowbase + r;
        float ax = 0.f, ay = 0.f;
        if (row < nrows) {
            int s = off[row], e = off[row + 1];
            int i = s;
            #pragma unroll 1
            for (; i + 3 < e; i += 4) {
                int2 c0 = csr[i], c1 = csr[i + 1], c2 = csr[i + 2], c3 = csr[i + 3];
                unsigned x0 = in[(size_t)c0.x * 64 + lane];
                unsigned x1 = in[(size_t)c1.x * 64 + lane];
                unsigned x2 = in[(size_t)c2.x * 64 + lane];
                unsigned x3 = in[(size_t)c3.x * 64 + lane];
                float v0 = __int_as_float(c0.y), v1 = __int_as_float(c1.y);
                float v2 = __int_as_float(c2.y), v3 = __int_as_float(c3.y);
                ax += v0 * blo(x0) + v1 * blo(x1) + v2 * blo(x2) + v3 * blo(x3);
                ay += v0 * bhi(x0) + v1 * bhi(x1) + v2 * bhi(x2) + v3 * bhi(x3);
            }
            #pragma unroll 1
            for (; i < e; ++i) {
                int2 cv = csr[i];
                unsigned x = in[(size_t)cv.x * 64 + lane];
                float v = __int_as_float(cv.y);
                ax += v * blo(x);
                ay += v * bhi(x);
            }
        }
        *(float2*)&acc_s[wave][r][2 * lane] = make_float2(ax, ay);
    }

    // --- dense 128x128 GEMM: o[r][j] = sum_k acc[r][k] * Wt[k][j] ---
    float2 o[R];
    #pragma unroll
    for (int r = 0; r < R; ++r) o[r] = make_float2(0.f, 0.f);
    #pragma unroll 4
    for (int k = 0; k < 128; k += 2) {
        float2 w0 = Wt[(size_t)k * 64 + lane];
        float2 w1 = Wt[(size_t)(k + 1) * 64 + lane];
        #pragma unroll
        for (int r = 0; r < R; ++r) {
            float b0 = acc_s[wave][r][k];
            float b1 = acc_s[wave][r][k + 1];
            o[r].x += b0 * w0.x + b1 * w1.x;
            o[r].y += b0 * w0.y + b1 * w1.y;
        }
    }

    // --- epilogue ---
    #pragma unroll 1
    for (int r = 0; r < R; ++r) {
        int row = rowbase + r;
        if (row >= nrows) break;
        float hx = fmaxf(o[r].x, 0.f), hy = fmaxf(o[r].y, 0.f);
        if (mode == 0) {
            out[(size_t)row * 64 + lane] = pack_bf16(hx, hy);
        } else {
            float2 e2 = emb[(size_t)row * 64 + lane];
            float ux = 0.3f * e2.x + 0.7f * hx;
            float uy = 0.3f * e2.y + 0.7f * hy;
            float s = ux + uy;
            #pragma unroll
            for (int d = 1; d < 64; d <<= 1) s += __shfl_xor(s, d);
            float mu = s * (1.f / 128.f);
            float dx = ux - mu, dy = uy - mu;
            float qv = dx * dx + dy * dy;
            #pragma unroll
            for (int d = 1; d < 64; d <<= 1) qv += __shfl_xor(qv, d);
            float rstd = rsqrtf(qv * (1.f / 128.f) + 1e-5f);
            float2 gg = *(const float2*)&g[2 * lane];
            float2 b2 = *(const float2*)&bb[2 * lane];
            float wx = dx * rstd * gg.x + b2.x + e2.x;   // word_H + emb_W fused
            float wy = dy * rstd * gg.y + b2.y + e2.y;
            out[(size_t)row * 64 + lane] = pack_bf16(wx, wy);
        }
    }
}

// ---------------------------------------------------------------------------
// Doc kernel: spmm(X, word_sum[bf16]) -> relu(. @ mlp_W^T + b) -> clf logits.
// Same register-budget pinning as layer_kernel.
// ---------------------------------------------------------------------------
template <int R>
__global__ __launch_bounds__(256, 8) void doc_kernel(
    const int* __restrict__ off, const int2* __restrict__ csr,
    const unsigned* __restrict__ in,          // bf16-packed word_sum [V][64]
    const float2* __restrict__ Wt,            // mlp_W transposed, float2 view
    const float* __restrict__ mlp_b, const float* __restrict__ clfW,
    const float* __restrict__ clfb,
    float* __restrict__ outp, int nrows) {

    __shared__ float acc_s[4][R][128];
    int lane = threadIdx.x & 63;
    int wave = threadIdx.x >> 6;
    int rowbase = (blockIdx.x * 4 + wave) * R;

    #pragma unroll 1
    for (int r = 0; r < R; ++r) {
        int row = rowbase + r;
        float ax = 0.f, ay = 0.f;
        if (row < nrows) {
            int s = off[row], e = off[row + 1];
            int i = s;
            #pragma unroll 1
            for (; i + 3 < e; i += 4) {
                int2 c0 = csr[i], c1 = csr[i + 1], c2 = csr[i + 2], c3 = csr[i + 3];
                unsigned x0 = in[(size_t)c0.x * 64 + lane];
                unsigned x1 = in[(size_t)c1.x * 64 + lane];
                unsigned x2 = in[(size_t)c2.x * 64 + lane];
                unsigned x3 = in[(size_t)c3.x * 64 + lane];
                float v0 = __int_as_float(c0.y), v1 = __int_as_float(c1.y);
                float v2 = __int_as_float(c2.y), v3 = __int_as_float(c3.y);
                ax += v0 * blo(x0) + v1 * blo(x1) + v2 * blo(x2) + v3 * blo(x3);
                ay += v0 * bhi(x0) + v1 * bhi(x1) + v2 * bhi(x2) + v3 * bhi(x3);
            }
            #pragma unroll 1
            for (; i < e; ++i) {
                int2 cv = csr[i];
                unsigned x = in[(size_t)cv.x * 64 + lane];
                float v = __int_as_float(cv.y);
                ax += v * blo(x);
                ay += v * bhi(x);
            }
        }
        *(float2*)&acc_s[wave][r][2 * lane] = make_float2(ax, ay);
    }

    float2 o[R];
    #pragma unroll
    for (int r = 0; r < R; ++r) o[r] = make_float2(0.f, 0.f);
    #pragma unroll 4
    for (int k = 0; k < 128; k += 2) {
        float2 w0 = Wt[(size_t)k * 64 + lane];
        float2 w1 = Wt[(size_t)(k + 1) * 64 + lane];
        #pragma unroll
        for (int r = 0; r < R; ++r) {
            float b0 = acc_s[wave][r][k];
            float b1 = acc_s[wave][r][k + 1];
            o[r].x += b0 * w0.x + b1 * w1.x;
            o[r].y += b0 * w0.y + b1 * w1.y;
        }
    }

    float2 mb = *(const float2*)&mlp_b[2 * lane];
    float2 c0 = *(const float2*)&clfW[2 * lane];
    float2 c1 = *(const float2*)&clfW[128 + 2 * lane];
    #pragma unroll 1
    for (int r = 0; r < R; ++r) {
        int row = rowbase + r;
        if (row >= nrows) break;
        float hx = fmaxf(o[r].x + mb.x, 0.f);
        float hy = fmaxf(o[r].y + mb.y, 0.f);
        float p0 = hx * c0.x + hy * c0.y;
        float p1 = hx * c1.x + hy * c1.y;
        #pragma unroll
        for (int d = 1; d < 64; d <<= 1) {
            p0 += __shfl_xor(p0, d);
            p1 += __shfl_xor(p1, d);
        }
        if (lane == 0) {
            outp[(size_t)row * 2 + 0] = p0 + clfb[0];
            outp[(size_t)row * 2 + 1] = p1 + clfb[1];
        }
    }
}

// ---------------------------------------------------------------------------
extern "C" void kernel_launch(void* const* d_in, const int* in_sizes, int n_in,
                              void* d_out, int out_size, void* d_ws, size_t ws_size,
                              hipStream_t stream) {
    const int*   A_row  = (const int*)d_in[0];
    const int*   A_col  = (const int*)d_in[1];
    const float* A_val  = (const float*)d_in[2];
    const int*   X_row  = (const int*)d_in[3];
    const int*   X_col  = (const int*)d_in[4];
    const float* X_val  = (const float*)d_in[5];
    const float* emb_W  = (const float*)d_in[6];
    const float* lin1_W = (const float*)d_in[7];
    const float* lin2_W = (const float*)d_in[8];
    const float* norm_g = (const float*)d_in[9];
    const float* norm_b = (const float*)d_in[10];
    const float* mlp_W  = (const float*)d_in[11];
    const float* mlp_b  = (const float*)d_in[12];
    const float* clf_W  = (const float*)d_in[13];
    const float* clf_b  = (const float*)d_in[14];

    const int E   = in_sizes[0];
    const int NNZ = in_sizes[3];
    const int V   = in_sizes[6] / 128;
    const int D   = out_size / 2;   // N_DOCS
    const int tot = E + NNZ;
    const int nchA = (V + 1023) / 1024;
    const int nchX = (D + 1023) / 1024;
    const int nbA = (V + RA - 1) / RA;   // 256
    const int nbX = (D + RX - 1) / RX;   // 254
    const int nb  = nbA + nbX;           // 510 <= NB_MAX

    // workspace carve-up (256B aligned)
    char* p = (char*)d_ws;
    auto alloc = [&](size_t bytes) -> void* {
        void* q = (void*)p;
        p += (bytes + 255) & ~(size_t)255;
        return q;
    };
    int*      curA   = (int*)alloc((size_t)V * 4);
    int*      offA   = (int*)alloc((size_t)(V + 1) * 4);
    int*      curX   = (int*)alloc((size_t)D * 4);
    int*      offX   = (int*)alloc((size_t)(D + 1) * 4);
    int*      chunkS = (int*)alloc((size_t)(nchA + nchX) * 4);
    int*      gcur   = (int*)alloc((size_t)nb * 4);
    int2*     csrA   = (int2*)alloc((size_t)E * 8);
    int2*     csrX   = (int2*)alloc((size_t)NNZ * 8);
    float*    Wt1    = (float*)alloc(128 * 128 * 4);
    float*    Wt2    = (float*)alloc(128 * 128 * 4);
    float*    Wt3    = (float*)alloc(128 * 128 * 4);
    unsigned* P_EMB  = (unsigned*)alloc((size_t)V * 64 * 4);
    // ebuf is dead after cluster_kernel; H1/WS alias it (stream-ordered).
    char*     ebuf_region = (char*)alloc((size_t)tot * 8 > 2 * (size_t)V * 64 * 4
                                         ? (size_t)tot * 8 : 2 * (size_t)V * 64 * 4);
    uint2*    ebuf  = (uint2*)ebuf_region;
    unsigned* P_H1  = (unsigned*)ebuf_region;
    unsigned* P_WS  = (unsigned*)(ebuf_region + (size_t)V * 64 * 4);

    hipMemsetAsync(curA, 0, (size_t)V * 4, stream);
    hipMemsetAsync(curX, 0, (size_t)D * 4, stream);

    hist_kernel<<<(tot + 255) / 256, 256, 0, stream>>>(A_row, E, X_row, NNZ, curA, curX);
    scan1_kernel<<<nchA + nchX, 1024, 0, stream>>>(curA, offA, V, nchA, curX, offX, D, chunkS);
    scan2_kernel<<<1, 128, 0, stream>>>(chunkS, nchA, nchX);
    scan3_kernel<<<(V + D + 255) / 256, 256, 0, stream>>>(curA, offA, V, nchA, curX, offX, D, chunkS);
    initg_kernel<<<(nb + 255) / 256, 256, 0, stream>>>(offA, offX, gcur, nbA, nb, V, D, E);
    partition_kernel<<<(tot + TILE_EDGES - 1) / TILE_EDGES, PT_THREADS, 0, stream>>>(
        A_row, A_col, A_val, E, X_row, X_col, X_val, NNZ, nbA, nb, gcur, ebuf);
    cluster_kernel<<<nb, 256, 0, stream>>>(
        ebuf, offA, offX, curA, curX, csrA, csrX, nbA, V, D, E);
    prep_kernel<<<(3 * 16384 + V * 64 + 255) / 256, 256, 0, stream>>>(
        lin1_W, lin2_W, mlp_W, Wt1, Wt2, Wt3, (const float2*)emb_W, P_EMB, V * 64);

    int layer_blocks = (V + 4 * 4 - 1) / (4 * 4);
    layer_kernel<4><<<layer_blocks, 256, 0, stream>>>(
        offA, csrA, P_EMB, (const float2*)Wt1,
        nullptr, nullptr, nullptr, P_H1, V, 0);
    layer_kernel<4><<<layer_blocks, 256, 0, stream>>>(
        offA, csrA, P_H1, (const float2*)Wt2,
        (const float2*)emb_W, norm_g, norm_b, P_WS, V, 1);

    int doc_blocks = (D + 4 * 4 - 1) / (4 * 4);
    doc_kernel<4><<<doc_blocks, 256, 0, stream>>>(
        offX, csrX, P_WS, (const float2*)Wt3,
        mlp_b, clf_W, clf_b, (float*)d_out, D);
}

// Round 7
// 689.569 us; speedup vs baseline: 7.2657x; 1.1554x over previous
//
#include <hip/hip_runtime.h>

#define NB_MAX 1024       // LDS counter capacity in partition kernel
#define RA 196            // rows per A-bucket  (256 buckets for V=50000)
#define RX 79             // rows per X-bucket  (254 buckets for D=20000)
#define PT_THREADS 512
#define PT_EPT 8          // edges per thread per partition tile (782 blocks)
#define TILE_EDGES (PT_THREADS * PT_EPT)
#define CSPLIT 4          // blocks per bucket in cluster_kernel

// ---- bf16 helpers: table uint at [row][l] packs cols (2l, 2l+1) ------------
__device__ __forceinline__ float blo(unsigned u) { return __uint_as_float(u << 16); }
__device__ __forceinline__ float bhi(unsigned u) { return __uint_as_float(u & 0xffff0000u); }
__device__ __forceinline__ unsigned pack_bf16(float x, float y) {
    unsigned ux = __float_as_uint(x); ux += 0x7fffu + ((ux >> 16) & 1u);
    unsigned uy = __float_as_uint(y); uy += 0x7fffu + ((uy >> 16) & 1u);
    return (ux >> 16) | (uy & 0xffff0000u);
}

// ---------------------------------------------------------------------------
// Row-level histogram (global atomics; counters are L2-resident).
// ---------------------------------------------------------------------------
__global__ void hist_kernel(const int* __restrict__ Arow, int nA,
                            const int* __restrict__ Xrow, int nX,
                            int* __restrict__ cntA, int* __restrict__ cntX) {
    int i = blockIdx.x * 256 + threadIdx.x;
    if (i < nA) {
        atomicAdd(&cntA[Arow[i]], 1);
    } else if (i < nA + nX) {
        atomicAdd(&cntX[Xrow[i - nA]], 1);
    }
}

// ---------------------------------------------------------------------------
// Hierarchical scan stage 1: block-local scan of 1024-row chunks.
// ---------------------------------------------------------------------------
__global__ __launch_bounds__(1024) void scan1_kernel(
    int* cntA, int* offA, int nA, int nchA,
    int* cntX, int* offX, int nX, int* chunkSums) {
    int b = blockIdx.x;
    int* cnt; int* off; int n; int cb;
    if (b < nchA) { cnt = cntA; off = offA; n = nA; cb = b; }
    else          { cnt = cntX; off = offX; n = nX; cb = b - nchA; }
    __shared__ int wsum[16];
    int tid = threadIdx.x, lane = tid & 63, w = tid >> 6;
    int i = cb * 1024 + tid;
    int x = (i < n) ? cnt[i] : 0;
    int v = x;
    #pragma unroll
    for (int d = 1; d < 64; d <<= 1) {
        int t = __shfl_up(v, d);
        if (lane >= d) v += t;
    }
    if (lane == 63) wsum[w] = v;
    __syncthreads();
    if (tid == 0) {
        int a = 0;
        #pragma unroll
        for (int j = 0; j < 16; ++j) { int t = wsum[j]; wsum[j] = a; a += t; }
        chunkSums[b] = a;
    }
    __syncthreads();
    int incl = v + wsum[w];
    if (i < n) { off[i + 1] = incl; cnt[i] = incl - x; }
}

// ---------------------------------------------------------------------------
// Stage 2: exclusive-scan chunk totals (wave 0: A chunks, wave 1: X chunks).
// ---------------------------------------------------------------------------
__global__ __launch_bounds__(128) void scan2_kernel(int* chunkSums, int nchA, int nchX) {
    int lane = threadIdx.x & 63;
    int w = threadIdx.x >> 6;
    int n    = (w == 0) ? nchA : nchX;
    int base = (w == 0) ? 0 : nchA;
    int carry = 0;
    for (int s = 0; s < n; s += 64) {
        int v = (s + lane < n) ? chunkSums[base + s + lane] : 0;
        int incl = v;
        #pragma unroll
        for (int d = 1; d < 64; d <<= 1) {
            int t = __shfl_up(incl, d);
            if (lane >= d) incl += t;
        }
        int tot = __shfl(incl, 63);
        int ex = __shfl_up(incl, 1);
        if (lane == 0) ex = 0;
        if (s + lane < n) chunkSums[base + s + lane] = carry + ex;
        carry += tot;
    }
}

// ---------------------------------------------------------------------------
// Stage 3: add chunk bases -> global row offsets + row cursors; off[0]=0.
// ---------------------------------------------------------------------------
__global__ void scan3_kernel(int* cntA, int* offA, int nA, int nchA,
                             int* cntX, int* offX, int nX,
                             const int* __restrict__ chunkSums) {
    int i = blockIdx.x * 256 + threadIdx.x;
    if (i < nA) {
        int b = chunkSums[i >> 10];
        cntA[i] += b; offA[i + 1] += b;
        if (i == 0) offA[0] = 0;
    } else {
        int j = i - nA;
        if (j < nX) {
            int b = chunkSums[nchA + (j >> 10)];
            cntX[j] += b; offX[j + 1] += b;
            if (j == 0) offX[0] = 0;
        }
    }
}

// ---------------------------------------------------------------------------
// Bucket cursors from row offsets (free: bucket start = off[first row]).
// ---------------------------------------------------------------------------
__global__ void initg_kernel(const int* __restrict__ offA, const int* __restrict__ offX,
                             int* __restrict__ gcur, int nbA, int nb, int V, int D, int E) {
    int b = blockIdx.x * 256 + threadIdx.x;
    if (b < nbA)      gcur[b] = offA[min(b * RA, V)];
    else if (b < nb)  gcur[b] = E + offX[min((b - nbA) * RX, D)];
}

// ---------------------------------------------------------------------------
// Partition edges into bucket-major ebuf with per-tile run reservation.
// Record: x = (row_local << 17) | col, y = bits(val).
// ---------------------------------------------------------------------------
__global__ __launch_bounds__(PT_THREADS) void partition_kernel(
    const int* __restrict__ Arow, const int* __restrict__ Acol, const float* __restrict__ Aval, int nA,
    const int* __restrict__ Xrow, const int* __restrict__ Xcol, const float* __restrict__ Xval, int nX,
    int nbA, int nb, int* __restrict__ gcur, uint2* __restrict__ ebuf) {
    __shared__ int cnt[NB_MAX];
    __shared__ int rbase[NB_MAX];
    for (int t = threadIdx.x; t < nb; t += PT_THREADS) cnt[t] = 0;
    __syncthreads();
    int tot = nA + nX;
    int t0 = blockIdx.x * TILE_EDGES;
    #pragma unroll 4
    for (int k = 0; k < PT_EPT; ++k) {
        int i = t0 + k * PT_THREADS + threadIdx.x;
        if (i < tot) {
            int b = (i < nA) ? (Arow[i] / RA) : (nbA + Xrow[i - nA] / RX);
            atomicAdd(&cnt[b], 1);
        }
    }
    __syncthreads();
    for (int t = threadIdx.x; t < nb; t += PT_THREADS) {
        int c = cnt[t];
        rbase[t] = c ? atomicAdd(&gcur[t], c) : 0;
        cnt[t] = 0;
    }
    __syncthreads();
    #pragma unroll 4
    for (int k = 0; k < PT_EPT; ++k) {
        int i = t0 + k * PT_THREADS + threadIdx.x;
        if (i < tot) {
            int b, rl, col; float val;
            if (i < nA) {
                int r = Arow[i]; b = r / RA; rl = r - b * RA;
                col = Acol[i]; val = Aval[i];
            } else {
                int j = i - nA; int r = Xrow[j]; int bx = r / RX;
                b = nbA + bx; rl = r - bx * RX;
                col = Xcol[j]; val = Xval[j];
            }
            int pos = rbase[b] + atomicAdd(&cnt[b], 1);
            ebuf[pos] = make_uint2(((unsigned)rl << 17) | (unsigned)col, __float_as_uint(val));
        }
    }
}

// ---------------------------------------------------------------------------
// Cluster: CSPLIT blocks per bucket scatter bucket edges to exact CSR slots.
// Random writes confined to the bucket's ~50-100 KB CSR span (L2-merged);
// row cursors shared via device atomics (split-safe).
// ---------------------------------------------------------------------------
__global__ __launch_bounds__(256) void cluster_kernel(
    const uint2* __restrict__ ebuf,
    const int* __restrict__ offA, const int* __restrict__ offX,
    int* __restrict__ curA, int* __restrict__ curX,
    int2* __restrict__ csrA, int2* __restrict__ csrX,
    int nbA, int V, int D, int E) {
    int b = blockIdx.x / CSPLIT;
    int c = blockIdx.x % CSPLIT;
    int r0, s, e; int* cur; int2* csr;
    if (b < nbA) {
        r0 = b * RA;
        s = offA[r0]; e = offA[min(r0 + RA, V)];
        cur = curA; csr = csrA;
    } else {
        int j = b - nbA;
        r0 = j * RX;
        s = E + offX[r0]; e = E + offX[min(r0 + RX, D)];
        cur = curX; csr = csrX;
    }
    int len = e - s;
    int cl = (len + CSPLIT - 1) / CSPLIT;
    int cs = s + c * cl;
    int ce = min(cs + cl, e);
    for (int i = cs + threadIdx.x; i < ce; i += 256) {
        uint2 rec = ebuf[i];
        int row = r0 + (rec.x >> 17);
        int p = atomicAdd(&cur[row], 1);
        csr[p] = make_int2(rec.x & 0x1FFFF, (int)rec.y);
    }
}

// ---------------------------------------------------------------------------
// Prep: transpose 128x128 weights (Wt[k][j] = W[j][k]) + emb -> packed bf16.
// ---------------------------------------------------------------------------
__global__ void prep_kernel(const float* __restrict__ W1, const float* __restrict__ W2,
                            const float* __restrict__ W3,
                            float* __restrict__ Wt1, float* __restrict__ Wt2,
                            float* __restrict__ Wt3,
                            const float2* __restrict__ emb, unsigned* __restrict__ emb16,
                            int nemb) {   // nemb = V*64
    int gid = blockIdx.x * 256 + threadIdx.x;
    if (gid < 3 * 16384) {
        int m = gid >> 14;
        int idx = gid & 16383;
        int j = idx >> 7;
        int k = idx & 127;
        const float* W = (m == 0) ? W1 : (m == 1) ? W2 : W3;
        float*      Wt = (m == 0) ? Wt1 : (m == 1) ? Wt2 : Wt3;
        Wt[k * 128 + j] = W[j * 128 + k];
    }
    int e = gid - 3 * 16384;
    if (e >= 0 && e < nemb) {
        float2 f = emb[e];
        emb16[e] = pack_bf16(f.x, f.y);
    }
}

// ---------------------------------------------------------------------------
// SpMM row gather-reduce, x8 in-flight 256 B gathers (latency MLP).
// ---------------------------------------------------------------------------
__device__ __forceinline__ void spmm_row8(const int2* __restrict__ csr, int s, int e,
                                          const unsigned* __restrict__ in, int lane,
                                          float& ax, float& ay) {
    int i = s;
    #pragma unroll 1
    for (; i + 7 < e; i += 8) {
        int2 c0 = csr[i],     c1 = csr[i + 1], c2 = csr[i + 2], c3 = csr[i + 3];
        int2 c4 = csr[i + 4], c5 = csr[i + 5], c6 = csr[i + 6], c7 = csr[i + 7];
        unsigned x0 = in[(size_t)c0.x * 64 + lane];
        unsigned x1 = in[(size_t)c1.x * 64 + lane];
        unsigned x2 = in[(size_t)c2.x * 64 + lane];
        unsigned x3 = in[(size_t)c3.x * 64 + lane];
        unsigned x4 = in[(size_t)c4.x * 64 + lane];
        unsigned x5 = in[(size_t)c5.x * 64 + lane];
        unsigned x6 = in[(size_t)c6.x * 64 + lane];
        unsigned x7 = in[(size_t)c7.x * 64 + lane];
        float v0 = __int_as_float(c0.y), v1 = __int_as_float(c1.y);
        float v2 = __int_as_float(c2.y), v3 = __int_as_float(c3.y);
        float v4 = __int_as_float(c4.y), v5 = __int_as_float(c5.y);
        float v6 = __int_as_float(c6.y), v7 = __int_as_float(c7.y);
        ax += v0 * blo(x0) + v1 * blo(x1) + v2 * blo(x2) + v3 * blo(x3)
            + v4 * blo(x4) + v5 * blo(x5) + v6 * blo(x6) + v7 * blo(x7);
        ay += v0 * bhi(x0) + v1 * bhi(x1) + v2 * bhi(x2) + v3 * bhi(x3)
            + v4 * bhi(x4) + v5 * bhi(x5) + v6 * bhi(x6) + v7 * bhi(x7);
    }
    #pragma unroll 1
    for (; i < e; ++i) {
        int2 cv = csr[i];
        unsigned x = in[(size_t)cv.x * 64 + lane];
        float v = __int_as_float(cv.y);
        ax += v * blo(x);
        ay += v * bhi(x);
    }
}

// ---------------------------------------------------------------------------
// Fused layer kernel. One wave owns R rows; lane l holds cols 2l, 2l+1.
// __launch_bounds__(256, 6): ~84-VGPR cap — room for the x8 edge unroll
// without an R5-style 204-VGPR blowup; occupancy cap 24 waves/CU.
//   mode 0: out = bf16(relu(spmm(A,in) @ W^T))
//   mode 1: t = relu(spmm(A,in) @ W^T); u = 0.3*emb + 0.7*t;
//           out = bf16(layernorm(u)*g + b + emb)   (word_H + emb_W pre-fused)
// ---------------------------------------------------------------------------
template <int R>
__global__ __launch_bounds__(256, 6) void layer_kernel(
    const int* __restrict__ off, const int2* __restrict__ csr,
    const unsigned* __restrict__ in,          // bf16-packed [nrows][64]
    const float2* __restrict__ Wt,            // [128][64] float2 view
    const float2* __restrict__ emb,           // fp32, mode 1 only
    const float* __restrict__ g, const float* __restrict__ bb,  // mode 1 only
    unsigned* __restrict__ out, int nrows, int mode) {

    __shared__ float acc_s[4][R][128];
    int lane = threadIdx.x & 63;
    int wave = threadIdx.x >> 6;
    int rowbase = (blockIdx.x * 4 + wave) * R;

    // --- SpMM into wave-private LDS ---
    #pragma unroll 1
    for (int r = 0; r < R; ++r) {
        int row = rowbase + r;
        float ax = 0.f, ay = 0.f;
        if (row < nrows) {
            spmm_row8(csr, off[row], off[row + 1], in, lane, ax, ay);
        }
        *(float2*)&acc_s[wave][r][2 * lane] = make_float2(ax, ay);
    }

    // --- dense 128x128 GEMM: o[r][j] = sum_k acc[r][k] * Wt[k][j] ---
    float2 o[R];
    #pragma unroll
    for (int r = 0; r < R; ++r) o[r] = make_float2(0.f, 0.f);
    #pragma unroll 4
    for (int k = 0; k < 128; k += 2) {
        float2 w0 = Wt[(size_t)k * 64 + lane];
        float2 w1 = Wt[(size_t)(k + 1) * 64 + lane];
        #pragma unroll
        for (int r = 0; r < R; ++r) {
            float b0 = acc_s[wave][r][k];
            float b1 = acc_s[wave][r][k + 1];
            o[r].x += b0 * w0.x + b1 * w1.x;
            o[r].y += b0 * w0.y + b1 * w1.y;
        }
    }

    // --- epilogue ---
    #pragma unroll 1
    for (int r = 0; r < R; ++r) {
        int row = rowbase + r;
        if (row >= nrows) break;
        float hx = fmaxf(o[r].x, 0.f), hy = fmaxf(o[r].y, 0.f);
        if (mode == 0) {
            out[(size_t)row * 64 + lane] = pack_bf16(hx, hy);
        } else {
            float2 e2 = emb[(size_t)row * 64 + lane];
            float ux = 0.3f * e2.x + 0.7f * hx;
            float uy = 0.3f * e2.y + 0.7f * hy;
            float s = ux + uy;
            #pragma unroll
            for (int d = 1; d < 64; d <<= 1) s += __shfl_xor(s, d);
            float mu = s * (1.f / 128.f);
            float dx = ux - mu, dy = uy - mu;
            float qv = dx * dx + dy * dy;
            #pragma unroll
            for (int d = 1; d < 64; d <<= 1) qv += __shfl_xor(qv, d);
            float rstd = rsqrtf(qv * (1.f / 128.f) + 1e-5f);
            float2 gg = *(const float2*)&g[2 * lane];
            float2 b2 = *(const float2*)&bb[2 * lane];
            float wx = dx * rstd * gg.x + b2.x + e2.x;   // word_H + emb_W fused
            float wy = dy * rstd * gg.y + b2.y + e2.y;
            out[(size_t)row * 64 + lane] = pack_bf16(wx, wy);
        }
    }
}

// ---------------------------------------------------------------------------
// Doc kernel: spmm(X, word_sum[bf16]) -> relu(. @ mlp_W^T + b) -> clf logits.
// ---------------------------------------------------------------------------
template <int R>
__global__ __launch_bounds__(256, 6) void doc_kernel(
    const int* __restrict__ off, const int2* __restrict__ csr,
    const unsigned* __restrict__ in,          // bf16-packed word_sum [V][64]
    const float2* __restrict__ Wt,            // mlp_W transposed, float2 view
    const float* __restrict__ mlp_b, const float* __restrict__ clfW,
    const float* __restrict__ clfb,
    float* __restrict__ outp, int nrows) {

    __shared__ float acc_s[4][R][128];
    int lane = threadIdx.x & 63;
    int wave = threadIdx.x >> 6;
    int rowbase = (blockIdx.x * 4 + wave) * R;

    #pragma unroll 1
    for (int r = 0; r < R; ++r) {
        int row = rowbase + r;
        float ax = 0.f, ay = 0.f;
        if (row < nrows) {
            spmm_row8(csr, off[row], off[row + 1], in, lane, ax, ay);
        }
        *(float2*)&acc_s[wave][r][2 * lane] = make_float2(ax, ay);
    }

    float2 o[R];
    #pragma unroll
    for (int r = 0; r < R; ++r) o[r] = make_float2(0.f, 0.f);
    #pragma unroll 4
    for (int k = 0; k < 128; k += 2) {
        float2 w0 = Wt[(size_t)k * 64 + lane];
        float2 w1 = Wt[(size_t)(k + 1) * 64 + lane];
        #pragma unroll
        for (int r = 0; r < R; ++r) {
            float b0 = acc_s[wave][r][k];
            float b1 = acc_s[wave][r][k + 1];
            o[r].x += b0 * w0.x + b1 * w1.x;
            o[r].y += b0 * w0.y + b1 * w1.y;
        }
    }

    float2 mb = *(const float2*)&mlp_b[2 * lane];
    float2 c0 = *(const float2*)&clfW[2 * lane];
    float2 c1 = *(const float2*)&clfW[128 + 2 * lane];
    #pragma unroll 1
    for (int r = 0; r < R; ++r) {
        int row = rowbase + r;
        if (row >= nrows) break;
        float hx = fmaxf(o[r].x + mb.x, 0.f);
        float hy = fmaxf(o[r].y + mb.y, 0.f);
        float p0 = hx * c0.x + hy * c0.y;
        float p1 = hx * c1.x + hy * c1.y;
        #pragma unroll
        for (int d = 1; d < 64; d <<= 1) {
            p0 += __shfl_xor(p0, d);
            p1 += __shfl_xor(p1, d);
        }
        if (lane == 0) {
            outp[(size_t)row * 2 + 0] = p0 + clfb[0];
            outp[(size_t)row * 2 + 1] = p1 + clfb[1];
        }
    }
}

// ---------------------------------------------------------------------------
extern "C" void kernel_launch(void* const* d_in, const int* in_sizes, int n_in,
                              void* d_out, int out_size, void* d_ws, size_t ws_size,
                              hipStream_t stream) {
    const int*   A_row  = (const int*)d_in[0];
    const int*   A_col  = (const int*)d_in[1];
    const float* A_val  = (const float*)d_in[2];
    const int*   X_row  = (const int*)d_in[3];
    const int*   X_col  = (const int*)d_in[4];
    const float* X_val  = (const float*)d_in[5];
    const float* emb_W  = (const float*)d_in[6];
    const float* lin1_W = (const float*)d_in[7];
    const float* lin2_W = (const float*)d_in[8];
    const float* norm_g = (const float*)d_in[9];
    const float* norm_b = (const float*)d_in[10];
    const float* mlp_W  = (const float*)d_in[11];
    const float* mlp_b  = (const float*)d_in[12];
    const float* clf_W  = (const float*)d_in[13];
    const float* clf_b  = (const float*)d_in[14];

    const int E   = in_sizes[0];
    const int NNZ = in_sizes[3];
    const int V   = in_sizes[6] / 128;
    const int D   = out_size / 2;   // N_DOCS
    const int tot = E + NNZ;
    const int nchA = (V + 1023) / 1024;
    const int nchX = (D + 1023) / 1024;
    const int nbA = (V + RA - 1) / RA;   // 256
    const int nbX = (D + RX - 1) / RX;   // 254
    const int nb  = nbA + nbX;           // 510 <= NB_MAX

    // workspace carve-up (256B aligned)
    char* p = (char*)d_ws;
    auto alloc = [&](size_t bytes) -> void* {
        void* q = (void*)p;
        p += (bytes + 255) & ~(size_t)255;
        return q;
    };
    int*      curA   = (int*)alloc((size_t)V * 4);
    int*      offA   = (int*)alloc((size_t)(V + 1) * 4);
    int*      curX   = (int*)alloc((size_t)D * 4);
    int*      offX   = (int*)alloc((size_t)(D + 1) * 4);
    int*      chunkS = (int*)alloc((size_t)(nchA + nchX) * 4);
    int*      gcur   = (int*)alloc((size_t)nb * 4);
    int2*     csrA   = (int2*)alloc((size_t)E * 8);
    int2*     csrX   = (int2*)alloc((size_t)NNZ * 8);
    float*    Wt1    = (float*)alloc(128 * 128 * 4);
    float*    Wt2    = (float*)alloc(128 * 128 * 4);
    float*    Wt3    = (float*)alloc(128 * 128 * 4);
    unsigned* P_EMB  = (unsigned*)alloc((size_t)V * 64 * 4);
    // ebuf is dead after cluster_kernel; H1/WS alias it (stream-ordered).
    char*     ebuf_region = (char*)alloc((size_t)tot * 8 > 2 * (size_t)V * 64 * 4
                                         ? (size_t)tot * 8 : 2 * (size_t)V * 64 * 4);
    uint2*    ebuf  = (uint2*)ebuf_region;
    unsigned* P_H1  = (unsigned*)ebuf_region;
    unsigned* P_WS  = (unsigned*)(ebuf_region + (size_t)V * 64 * 4);

    hipMemsetAsync(curA, 0, (size_t)V * 4, stream);
    hipMemsetAsync(curX, 0, (size_t)D * 4, stream);

    hist_kernel<<<(tot + 255) / 256, 256, 0, stream>>>(A_row, E, X_row, NNZ, curA, curX);
    scan1_kernel<<<nchA + nchX, 1024, 0, stream>>>(curA, offA, V, nchA, curX, offX, D, chunkS);
    scan2_kernel<<<1, 128, 0, stream>>>(chunkS, nchA, nchX);
    scan3_kernel<<<(V + D + 255) / 256, 256, 0, stream>>>(curA, offA, V, nchA, curX, offX, D, chunkS);
    initg_kernel<<<(nb + 255) / 256, 256, 0, stream>>>(offA, offX, gcur, nbA, nb, V, D, E);
    partition_kernel<<<(tot + TILE_EDGES - 1) / TILE_EDGES, PT_THREADS, 0, stream>>>(
        A_row, A_col, A_val, E, X_row, X_col, X_val, NNZ, nbA, nb, gcur, ebuf);
    cluster_kernel<<<nb * CSPLIT, 256, 0, stream>>>(
        ebuf, offA, offX, curA, curX, csrA, csrX, nbA, V, D, E);
    prep_kernel<<<(3 * 16384 + V * 64 + 255) / 256, 256, 0, stream>>>(
        lin1_W, lin2_W, mlp_W, Wt1, Wt2, Wt3, (const float2*)emb_W, P_EMB, V * 64);

    int layer_blocks = (V + 4 * 4 - 1) / (4 * 4);
    layer_kernel<4><<<layer_blocks, 256, 0, stream>>>(
        offA, csrA, P_EMB, (const float2*)Wt1,
        nullptr, nullptr, nullptr, P_H1, V, 0);
    layer_kernel<4><<<layer_blocks, 256, 0, stream>>>(
        offA, csrA, P_H1, (const float2*)Wt2,
        (const float2*)emb_W, norm_g, norm_b, P_WS, V, 1);

    int doc_blocks = (D + 4 * 4 - 1) / (4 * 4);
    doc_kernel<4><<<doc_blocks, 256, 0, stream>>>(
        offX, csrX, P_WS, (const float2*)Wt3,
        mlp_b, clf_W, clf_b, (float*)d_out, D);
}

// Round 8
// 524.923 us; speedup vs baseline: 9.5447x; 1.3137x over previous
//
#include <hip/hip_runtime.h>

#define NB_MAX 1024       // LDS counter capacity (bhist / partition)
#define RA 196            // rows per A-bucket  (256 buckets for V=50000)
#define RX 79             // rows per X-bucket  (254 buckets for D=20000)
#define PT_THREADS 512
#define PT_EPT 8          // edges per thread per partition tile (782 blocks)
#define TILE_EDGES (PT_THREADS * PT_EPT)

// ---- bf16 helpers: table uint at [row][l] packs cols (2l, 2l+1) ------------
__device__ __forceinline__ float blo(unsigned u) { return __uint_as_float(u << 16); }
__device__ __forceinline__ float bhi(unsigned u) { return __uint_as_float(u & 0xffff0000u); }
__device__ __forceinline__ unsigned pack_bf16(float x, float y) {
    unsigned ux = __float_as_uint(x); ux += 0x7fffu + ((ux >> 16) & 1u);
    unsigned uy = __float_as_uint(y); uy += 0x7fffu + ((uy >> 16) & 1u);
    return (ux >> 16) | (uy & 0xffff0000u);
}

// ---------------------------------------------------------------------------
// Bucket-level histogram, LDS-aggregated (510 counters; ~510 global atomics
// per block instead of 3.2M row-level ones — R7's hist_kernel cost 137 µs
// and 99 MB of HBM writeback from device-scope atomic RMWs).
// ---------------------------------------------------------------------------
__global__ __launch_bounds__(256) void bhist_kernel(
    const int* __restrict__ Arow, int nA, const int* __restrict__ Xrow, int nX,
    int nbA, int nb, int* __restrict__ gcnt) {
    __shared__ int cnt[NB_MAX];
    for (int t = threadIdx.x; t < nb; t += 256) cnt[t] = 0;
    __syncthreads();
    int tot = nA + nX;
    for (int i = blockIdx.x * 256 + threadIdx.x; i < tot; i += gridDim.x * 256) {
        int b = (i < nA) ? (Arow[i] / RA) : (nbA + Xrow[i - nA] / RX);
        atomicAdd(&cnt[b], 1);
    }
    __syncthreads();
    for (int t = threadIdx.x; t < nb; t += 256)
        if (cnt[t]) atomicAdd(&gcnt[t], cnt[t]);
}

// ---------------------------------------------------------------------------
// Single-block exclusive scan of nb (<=1024) bucket counts -> boff, gcur.
// ---------------------------------------------------------------------------
__global__ __launch_bounds__(1024) void bscan_kernel(
    const int* __restrict__ gcnt, int* __restrict__ boff, int* __restrict__ gcur, int nb) {
    __shared__ int wsum[16];
    int tid = threadIdx.x, lane = tid & 63, w = tid >> 6;
    int x = (tid < nb) ? gcnt[tid] : 0;
    int v = x;
    #pragma unroll
    for (int d = 1; d < 64; d <<= 1) {
        int t = __shfl_up(v, d);
        if (lane >= d) v += t;
    }
    if (lane == 63) wsum[w] = v;
    __syncthreads();
    if (tid == 0) {
        int a = 0;
        #pragma unroll
        for (int j = 0; j < 16; ++j) { int t = wsum[j]; wsum[j] = a; a += t; }
    }
    __syncthreads();
    int incl = v + wsum[w];
    if (tid < nb) { boff[tid + 1] = incl; gcur[tid] = incl - x; }
    if (tid == 0) boff[0] = 0;
}

// ---------------------------------------------------------------------------
// Partition edges into bucket-major ebuf with per-tile run reservation.
// Record: x = (row_local << 17) | col, y = bits(val).
// A buckets land in ebuf[0,E), X buckets in ebuf[E, E+NNZ) (scan order).
// ---------------------------------------------------------------------------
__global__ __launch_bounds__(PT_THREADS) void partition_kernel(
    const int* __restrict__ Arow, const int* __restrict__ Acol, const float* __restrict__ Aval, int nA,
    const int* __restrict__ Xrow, const int* __restrict__ Xcol, const float* __restrict__ Xval, int nX,
    int nbA, int nb, int* __restrict__ gcur, uint2* __restrict__ ebuf) {
    __shared__ int cnt[NB_MAX];
    __shared__ int rbase[NB_MAX];
    for (int t = threadIdx.x; t < nb; t += PT_THREADS) cnt[t] = 0;
    __syncthreads();
    int tot = nA + nX;
    int t0 = blockIdx.x * TILE_EDGES;
    #pragma unroll 4
    for (int k = 0; k < PT_EPT; ++k) {
        int i = t0 + k * PT_THREADS + threadIdx.x;
        if (i < tot) {
            int b = (i < nA) ? (Arow[i] / RA) : (nbA + Xrow[i - nA] / RX);
            atomicAdd(&cnt[b], 1);
        }
    }
    __syncthreads();
    for (int t = threadIdx.x; t < nb; t += PT_THREADS) {
        int c = cnt[t];
        rbase[t] = c ? atomicAdd(&gcur[t], c) : 0;
        cnt[t] = 0;
    }
    __syncthreads();
    #pragma unroll 4
    for (int k = 0; k < PT_EPT; ++k) {
        int i = t0 + k * PT_THREADS + threadIdx.x;
        if (i < tot) {
            int b, rl, col; float val;
            if (i < nA) {
                int r = Arow[i]; b = r / RA; rl = r - b * RA;
                col = Acol[i]; val = Aval[i];
            } else {
                int j = i - nA; int r = Xrow[j]; int bx = r / RX;
                b = nbA + bx; rl = r - bx * RX;
                col = Xcol[j]; val = Xval[j];
            }
            int pos = rbase[b] + atomicAdd(&cnt[b], 1);
            ebuf[pos] = make_uint2(((unsigned)rl << 17) | (unsigned)col, __float_as_uint(val));
        }
    }
}

// ---------------------------------------------------------------------------
// Cluster v2: one block per bucket builds the bucket's row-level CSR locally.
// pass1: LDS row histogram (<=196 counters, LDS atomics). wave-0 scan ->
// exclusive offsets; write off[] slice (bucket-private; boundaries agree).
// pass2: scatter via LDS cursors. Zero row-level global atomics.
// ---------------------------------------------------------------------------
__global__ __launch_bounds__(1024) void cluster2_kernel(
    const uint2* __restrict__ ebuf, const int* __restrict__ boff,
    int* __restrict__ offA, int* __restrict__ offX,
    int2* __restrict__ csrA, int2* __restrict__ csrX,
    int nbA, int V, int D, int E) {
    __shared__ int rcnt[RA + 1];
    __shared__ int lcur[RA];
    int b = blockIdx.x;
    int r0, rows; int* off; int2* csr; int base_sub;
    if (b < nbA) {
        r0 = b * RA; rows = min(V - r0, RA);
        off = offA; csr = csrA; base_sub = 0;
    } else {
        int j = b - nbA;
        r0 = j * RX; rows = min(D - r0, RX);
        off = offX; csr = csrX; base_sub = E;
    }
    int s = boff[b], e = boff[b + 1];
    int base = s - base_sub;

    for (int t = threadIdx.x; t <= rows; t += 1024) rcnt[t] = 0;
    __syncthreads();
    for (int i = s + threadIdx.x; i < e; i += 1024)
        atomicAdd(&rcnt[ebuf[i].x >> 17], 1);
    __syncthreads();

    // wave 0: exclusive scan of rcnt[0..rows) in place; rcnt[rows] = total
    if (threadIdx.x < 64) {
        int lane = threadIdx.x;
        int carry = 0;
        for (int sb = 0; sb < rows; sb += 64) {
            int idx = sb + lane;
            int v = (idx < rows) ? rcnt[idx] : 0;
            int incl = v;
            #pragma unroll
            for (int d = 1; d < 64; d <<= 1) {
                int t = __shfl_up(incl, d);
                if (lane >= d) incl += t;
            }
            int tot = __shfl(incl, 63);
            if (idx < rows) rcnt[idx] = carry + incl - v;
            carry += tot;
        }
        if (lane == 0) rcnt[rows] = carry;
    }
    __syncthreads();

    for (int t = threadIdx.x; t <= rows; t += 1024) {
        off[r0 + t] = base + rcnt[t];
        if (t < rows) lcur[t] = rcnt[t];
    }
    __syncthreads();

    for (int i = s + threadIdx.x; i < e; i += 1024) {
        uint2 rec = ebuf[i];
        int rl = rec.x >> 17;
        int p = base + atomicAdd(&lcur[rl], 1);
        csr[p] = make_int2(rec.x & 0x1FFFF, (int)rec.y);
    }
}

// ---------------------------------------------------------------------------
// Prep: transpose 128x128 weights (Wt[k][j] = W[j][k]) + emb -> packed bf16.
// ---------------------------------------------------------------------------
__global__ void prep_kernel(const float* __restrict__ W1, const float* __restrict__ W2,
                            const float* __restrict__ W3,
                            float* __restrict__ Wt1, float* __restrict__ Wt2,
                            float* __restrict__ Wt3,
                            const float2* __restrict__ emb, unsigned* __restrict__ emb16,
                            int nemb) {   // nemb = V*64
    int gid = blockIdx.x * 256 + threadIdx.x;
    if (gid < 3 * 16384) {
        int m = gid >> 14;
        int idx = gid & 16383;
        int j = idx >> 7;
        int k = idx & 127;
        const float* W = (m == 0) ? W1 : (m == 1) ? W2 : W3;
        float*      Wt = (m == 0) ? Wt1 : (m == 1) ? Wt2 : Wt3;
        Wt[k * 128 + j] = W[j * 128 + k];
    }
    int e = gid - 3 * 16384;
    if (e >= 0 && e < nemb) {
        float2 f = emb[e];
        emb16[e] = pack_bf16(f.x, f.y);
    }
}

// ---------------------------------------------------------------------------
// SpMM row gather-reduce, x8 in-flight 256 B gathers (latency MLP).
// ---------------------------------------------------------------------------
__device__ __forceinline__ void spmm_row8(const int2* __restrict__ csr, int s, int e,
                                          const unsigned* __restrict__ in, int lane,
                                          float& ax, float& ay) {
    int i = s;
    #pragma unroll 1
    for (; i + 7 < e; i += 8) {
        int2 c0 = csr[i],     c1 = csr[i + 1], c2 = csr[i + 2], c3 = csr[i + 3];
        int2 c4 = csr[i + 4], c5 = csr[i + 5], c6 = csr[i + 6], c7 = csr[i + 7];
        unsigned x0 = in[(size_t)c0.x * 64 + lane];
        unsigned x1 = in[(size_t)c1.x * 64 + lane];
        unsigned x2 = in[(size_t)c2.x * 64 + lane];
        unsigned x3 = in[(size_t)c3.x * 64 + lane];
        unsigned x4 = in[(size_t)c4.x * 64 + lane];
        unsigned x5 = in[(size_t)c5.x * 64 + lane];
        unsigned x6 = in[(size_t)c6.x * 64 + lane];
        unsigned x7 = in[(size_t)c7.x * 64 + lane];
        float v0 = __int_as_float(c0.y), v1 = __int_as_float(c1.y);
        float v2 = __int_as_float(c2.y), v3 = __int_as_float(c3.y);
        float v4 = __int_as_float(c4.y), v5 = __int_as_float(c5.y);
        float v6 = __int_as_float(c6.y), v7 = __int_as_float(c7.y);
        ax += v0 * blo(x0) + v1 * blo(x1) + v2 * blo(x2) + v3 * blo(x3)
            + v4 * blo(x4) + v5 * blo(x5) + v6 * blo(x6) + v7 * blo(x7);
        ay += v0 * bhi(x0) + v1 * bhi(x1) + v2 * bhi(x2) + v3 * bhi(x3)
            + v4 * bhi(x4) + v5 * bhi(x5) + v6 * bhi(x6) + v7 * bhi(x7);
    }
    #pragma unroll 1
    for (; i < e; ++i) {
        int2 cv = csr[i];
        unsigned x = in[(size_t)cv.x * 64 + lane];
        float v = __int_as_float(cv.y);
        ax += v * blo(x);
        ay += v * bhi(x);
    }
}

// ---------------------------------------------------------------------------
// Fused layer kernel. One wave owns R rows; lane l holds cols 2l, 2l+1.
// __launch_bounds__(256, 6): ~84-VGPR cap (R5's unbounded build hit 204).
//   mode 0: out = bf16(relu(spmm(A,in) @ W^T))
//   mode 1: t = relu(spmm(A,in) @ W^T); u = 0.3*emb + 0.7*t;
//           out = bf16(layernorm(u)*g + b + emb)   (word_H + emb_W pre-fused)
// ---------------------------------------------------------------------------
template <int R>
__global__ __launch_bounds__(256, 6) void layer_kernel(
    const int* __restrict__ off, const int2* __restrict__ csr,
    const unsigned* __restrict__ in,          // bf16-packed [nrows][64]
    const float2* __restrict__ Wt,            // [128][64] float2 view
    const float2* __restrict__ emb,           // fp32, mode 1 only
    const float* __restrict__ g, const float* __restrict__ bb,  // mode 1 only
    unsigned* __restrict__ out, int nrows, int mode) {

    __shared__ float acc_s[4][R][128];
    int lane = threadIdx.x & 63;
    int wave = threadIdx.x >> 6;
    int rowbase = (blockIdx.x * 4 + wave) * R;

    #pragma unroll 1
    for (int r = 0; r < R; ++r) {
        int row = rowbase + r;
        float ax = 0.f, ay = 0.f;
        if (row < nrows) {
            spmm_row8(csr, off[row], off[row + 1], in, lane, ax, ay);
        }
        *(float2*)&acc_s[wave][r][2 * lane] = make_float2(ax, ay);
    }

    float2 o[R];
    #pragma unroll
    for (int r = 0; r < R; ++r) o[r] = make_float2(0.f, 0.f);
    #pragma unroll 4
    for (int k = 0; k < 128; k += 2) {
        float2 w0 = Wt[(size_t)k * 64 + lane];
        float2 w1 = Wt[(size_t)(k + 1) * 64 + lane];
        #pragma unroll
        for (int r = 0; r < R; ++r) {
            float b0 = acc_s[wave][r][k];
            float b1 = acc_s[wave][r][k + 1];
            o[r].x += b0 * w0.x + b1 * w1.x;
            o[r].y += b0 * w0.y + b1 * w1.y;
        }
    }

    #pragma unroll 1
    for (int r = 0; r < R; ++r) {
        int row = rowbase + r;
        if (row >= nrows) break;
        float hx = fmaxf(o[r].x, 0.f), hy = fmaxf(o[r].y, 0.f);
        if (mode == 0) {
            out[(size_t)row * 64 + lane] = pack_bf16(hx, hy);
        } else {
            float2 e2 = emb[(size_t)row * 64 + lane];
            float ux = 0.3f * e2.x + 0.7f * hx;
            float uy = 0.3f * e2.y + 0.7f * hy;
            float s = ux + uy;
            #pragma unroll
            for (int d = 1; d < 64; d <<= 1) s += __shfl_xor(s, d);
            float mu = s * (1.f / 128.f);
            float dx = ux - mu, dy = uy - mu;
            float qv = dx * dx + dy * dy;
            #pragma unroll
            for (int d = 1; d < 64; d <<= 1) qv += __shfl_xor(qv, d);
            float rstd = rsqrtf(qv * (1.f / 128.f) + 1e-5f);
            float2 gg = *(const float2*)&g[2 * lane];
            float2 b2 = *(const float2*)&bb[2 * lane];
            float wx = dx * rstd * gg.x + b2.x + e2.x;   // word_H + emb_W fused
            float wy = dy * rstd * gg.y + b2.y + e2.y;
            out[(size_t)row * 64 + lane] = pack_bf16(wx, wy);
        }
    }
}

// ---------------------------------------------------------------------------
// Doc kernel: spmm(X, word_sum[bf16]) -> relu(. @ mlp_W^T + b) -> clf logits.
// ---------------------------------------------------------------------------
template <int R>
__global__ __launch_bounds__(256, 6) void doc_kernel(
    const int* __restrict__ off, const int2* __restrict__ csr,
    const unsigned* __restrict__ in,          // bf16-packed word_sum [V][64]
    const float2* __restrict__ Wt,            // mlp_W transposed, float2 view
    const float* __restrict__ mlp_b, const float* __restrict__ clfW,
    const float* __restrict__ clfb,
    float* __restrict__ outp, int nrows) {

    __shared__ float acc_s[4][R][128];
    int lane = threadIdx.x & 63;
    int wave = threadIdx.x >> 6;
    int rowbase = (blockIdx.x * 4 + wave) * R;

    #pragma unroll 1
    for (int r = 0; r < R; ++r) {
        int row = rowbase + r;
        float ax = 0.f, ay = 0.f;
        if (row < nrows) {
            spmm_row8(csr, off[row], off[row + 1], in, lane, ax, ay);
        }
        *(float2*)&acc_s[wave][r][2 * lane] = make_float2(ax, ay);
    }

    float2 o[R];
    #pragma unroll
    for (int r = 0; r < R; ++r) o[r] = make_float2(0.f, 0.f);
    #pragma unroll 4
    for (int k = 0; k < 128; k += 2) {
        float2 w0 = Wt[(size_t)k * 64 + lane];
        float2 w1 = Wt[(size_t)(k + 1) * 64 + lane];
        #pragma unroll
        for (int r = 0; r < R; ++r) {
            float b0 = acc_s[wave][r][k];
            float b1 = acc_s[wave][r][k + 1];
            o[r].x += b0 * w0.x + b1 * w1.x;
            o[r].y += b0 * w0.y + b1 * w1.y;
        }
    }

    float2 mb = *(const float2*)&mlp_b[2 * lane];
    float2 c0 = *(const float2*)&clfW[2 * lane];
    float2 c1 = *(const float2*)&clfW[128 + 2 * lane];
    #pragma unroll 1
    for (int r = 0; r < R; ++r) {
        int row = rowbase + r;
        if (row >= nrows) break;
        float hx = fmaxf(o[r].x + mb.x, 0.f);
        float hy = fmaxf(o[r].y + mb.y, 0.f);
        float p0 = hx * c0.x + hy * c0.y;
        float p1 = hx * c1.x + hy * c1.y;
        #pragma unroll
        for (int d = 1; d < 64; d <<= 1) {
            p0 += __shfl_xor(p0, d);
            p1 += __shfl_xor(p1, d);
        }
        if (lane == 0) {
            outp[(size_t)row * 2 + 0] = p0 + clfb[0];
            outp[(size_t)row * 2 + 1] = p1 + clfb[1];
        }
    }
}

// ---------------------------------------------------------------------------
extern "C" void kernel_launch(void* const* d_in, const int* in_sizes, int n_in,
                              void* d_out, int out_size, void* d_ws, size_t ws_size,
                              hipStream_t stream) {
    const int*   A_row  = (const int*)d_in[0];
    const int*   A_col  = (const int*)d_in[1];
    const float* A_val  = (const float*)d_in[2];
    const int*   X_row  = (const int*)d_in[3];
    const int*   X_col  = (const int*)d_in[4];
    const float* X_val  = (const float*)d_in[5];
    const float* emb_W  = (const float*)d_in[6];
    const float* lin1_W = (const float*)d_in[7];
    const float* lin2_W = (const float*)d_in[8];
    const float* norm_g = (const float*)d_in[9];
    const float* norm_b = (const float*)d_in[10];
    const float* mlp_W  = (const float*)d_in[11];
    const float* mlp_b  = (const float*)d_in[12];
    const float* clf_W  = (const float*)d_in[13];
    const float* clf_b  = (const float*)d_in[14];

    const int E   = in_sizes[0];
    const int NNZ = in_sizes[3];
    const int V   = in_sizes[6] / 128;
    const int D   = out_size / 2;   // N_DOCS
    const int tot = E + NNZ;
    const int nbA = (V + RA - 1) / RA;   // 256
    const int nbX = (D + RX - 1) / RX;   // 254
    const int nb  = nbA + nbX;           // 510 <= NB_MAX

    // workspace carve-up (256B aligned)
    char* p = (char*)d_ws;
    auto alloc = [&](size_t bytes) -> void* {
        void* q = (void*)p;
        p += (bytes + 255) & ~(size_t)255;
        return q;
    };
    int*      offA   = (int*)alloc((size_t)(V + 1) * 4);
    int*      offX   = (int*)alloc((size_t)(D + 1) * 4);
    int*      gcnt   = (int*)alloc((size_t)nb * 4);
    int*      boff   = (int*)alloc((size_t)(nb + 1) * 4);
    int*      gcur   = (int*)alloc((size_t)nb * 4);
    int2*     csrA   = (int2*)alloc((size_t)E * 8);
    int2*     csrX   = (int2*)alloc((size_t)NNZ * 8);
    float*    Wt1    = (float*)alloc(128 * 128 * 4);
    float*    Wt2    = (float*)alloc(128 * 128 * 4);
    float*    Wt3    = (float*)alloc(128 * 128 * 4);
    unsigned* P_EMB  = (unsigned*)alloc((size_t)V * 64 * 4);
    // ebuf is dead after cluster2_kernel; H1/WS alias it (stream-ordered).
    char*     ebuf_region = (char*)alloc((size_t)tot * 8 > 2 * (size_t)V * 64 * 4
                                         ? (size_t)tot * 8 : 2 * (size_t)V * 64 * 4);
    uint2*    ebuf  = (uint2*)ebuf_region;
    unsigned* P_H1  = (unsigned*)ebuf_region;
    unsigned* P_WS  = (unsigned*)(ebuf_region + (size_t)V * 64 * 4);

    hipMemsetAsync(gcnt, 0, (size_t)nb * 4, stream);

    bhist_kernel<<<512, 256, 0, stream>>>(A_row, E, X_row, NNZ, nbA, nb, gcnt);
    bscan_kernel<<<1, 1024, 0, stream>>>(gcnt, boff, gcur, nb);
    partition_kernel<<<(tot + TILE_EDGES - 1) / TILE_EDGES, PT_THREADS, 0, stream>>>(
        A_row, A_col, A_val, E, X_row, X_col, X_val, NNZ, nbA, nb, gcur, ebuf);
    cluster2_kernel<<<nb, 1024, 0, stream>>>(
        ebuf, boff, offA, offX, csrA, csrX, nbA, V, D, E);
    prep_kernel<<<(3 * 16384 + V * 64 + 255) / 256, 256, 0, stream>>>(
        lin1_W, lin2_W, mlp_W, Wt1, Wt2, Wt3, (const float2*)emb_W, P_EMB, V * 64);

    int layer_blocks = (V + 4 * 4 - 1) / (4 * 4);
    layer_kernel<4><<<layer_blocks, 256, 0, stream>>>(
        offA, csrA, P_EMB, (const float2*)Wt1,
        nullptr, nullptr, nullptr, P_H1, V, 0);
    layer_kernel<4><<<layer_blocks, 256, 0, stream>>>(
        offA, csrA, P_H1, (const float2*)Wt2,
        (const float2*)emb_W, norm_g, norm_b, P_WS, V, 1);

    int doc_blocks = (D + 4 * 4 - 1) / (4 * 4);
    doc_kernel<4><<<doc_blocks, 256, 0, stream>>>(
        offX, csrX, P_WS, (const float2*)Wt3,
        mlp_b, clf_W, clf_b, (float*)d_out, D);
}